// Round 26
// baseline (220.119 us; speedup 1.0000x reference)
//
#include <hip/hip_runtime.h>
#include <math.h>

// Problem constants: N=8, C=128, H=64, W=64, B=N*W=512, ADJ=33, G=8, GP=16
constexpr float EPSV = 1e-5f;
typedef unsigned short u16;
using bf16x8 = __attribute__((ext_vector_type(8))) short;
using f32x4  = __attribute__((ext_vector_type(4))) float;

// ---------------- workspace layout (offsets in floats) ----------------
constexpr size_t F_W127  = 0;
constexpr size_t F_W64   = F_W127 + 4224;
constexpr size_t F_QKVST = F_W64  + 2112;
constexpr size_t F_SIMST = F_QKVST+ 512;
constexpr size_t F_SOST  = F_SIMST+ 384;
constexpr size_t F_INST  = F_SOST + 512;
constexpr size_t F_POSTMP= F_INST + 2048;          // 134112 (pos1 tmp; dead after pos2)
constexpr size_t F_POS   = F_POSTMP + 134112;      // 34848
constexpr size_t F_QKV   = F_POS  + 34848;         // qkvT u16 [512][64][256] (alias: SO u16 later)
constexpr size_t F_QKVR  = F_QKV  + 8388608;       // qkvrT u16 [512][33][256]
constexpr size_t F_SIM   = F_QKVR + 4325376;       // sim u16 13381632 elems (alias: XQ early, h1T later)
constexpr size_t F_PART6 = F_SIM  + 13381632;      // region: part6 / part2(so-stats) / bnp / opart / wqb / w1b / w2b
constexpr size_t F_VEH   = F_PART6 + 4460544;      // VeP u16 33792 elems
constexpr size_t F_XNT   = F_VEH  + 33792;         // xnT bf16 = 2097152 f
constexpr size_t F_KET   = F_XNT  + 2097152;       // keT 8712
constexpr size_t F_SO    = F_QKV;                  // so u16 [512][256][64] (after qkvT dead)
constexpr size_t F_XQ    = F_SIM;                  // xq bf16 [512][64][128] (dies before k_sim)
constexpr size_t F_BNP2  = F_PART6 + 262144;       // qkv BN partials; then opart (k_o..k_instB)
constexpr size_t F_WQB   = F_PART6 + 524288;       // wqb bf16 [256][128]
constexpr size_t F_H1    = F_SIM + 4194304;        // h1T bf16 (written after sim dead)
// w1b/w2b in PART6 dead sub-range (all other PART6 users stay below offset 540672).
constexpr size_t F_W1B   = F_PART6 + 1048576;      // 32768 floats (65536 u16)
constexpr size_t F_W2B   = F_PART6 + 1081344;      // 32768 floats

__device__ __forceinline__ u16 f2b(float x){      // fp32 -> bf16 RNE
  unsigned u = __float_as_uint(x);
  return (u16)((u + 0x7FFFu + ((u>>16)&1u)) >> 16);
}
__device__ __forceinline__ float b2f(u16 v){      // bf16 -> fp32
  return __uint_as_float((unsigned)v << 16);
}

// branch-free erf (Abramowitz-Stegun 7.1.26, max abs err 1.5e-7) + exact GELU
__device__ __forceinline__ float gelu_f(float v){
  float x = v*0.70710678f;
  float ax = fabsf(x);
  float t = __frcp_rn(1.0f + 0.3275911f*ax);   // v_rcp-based
  float p = 1.061405429f;
  p = p*t - 1.453152027f;
  p = p*t + 1.421413741f;
  p = p*t - 0.284496736f;
  p = p*t + 0.254829592f;
  p = p*t;
  float e = __expf(-ax*ax);
  float y = 1.0f - p*e;                        // erf(|x|)
  float er = copysignf(y, x);
  return 0.5f*v*(1.0f + er);
}

// ---- compile-time 33->64 upsample tables ----
struct UpT { int j0[64]; float fj[64]; };
constexpr UpT mkUp(){
  UpT t{};
  for (int o=0;o<64;++o){
    float x = ((float)o + 0.5f)*0.515625f - 0.5f;
    if (x < 0.f) x = 0.f;
    if (x > 32.f) x = 32.f;
    int j = (int)x; if (j > 31) j = 31;
    t.j0[o] = j; t.fj[o] = x - (float)j;
  }
  return t;
}
constexpr UpT UT = mkUp();

__device__ __forceinline__ void upfac(int o, int& j0, float& f){
  float x = ((float)o + 0.5f)*0.515625f - 0.5f;
  x = fminf(fmaxf(x, 0.f), 32.f);
  int j = (int)x; j = j < 31 ? j : 31;
  j0 = j; f = x - (float)j;
}

__device__ __forceinline__ void fma8(float (&a)[8], float qv, const float4& q0, const float4& q1){
  a[0] += qv*q0.x; a[1] += qv*q0.y; a[2] += qv*q0.z; a[3] += qv*q0.w;
  a[4] += qv*q1.x; a[5] += qv*q1.y; a[6] += qv*q1.z; a[7] += qv*q1.w;
}
__device__ __forceinline__ void fma8h(float (&a)[8], float qv, uint4 u){
  a[0] += qv*b2f((u16)(u.x&0xFFFFu)); a[1] += qv*b2f((u16)(u.x>>16));
  a[2] += qv*b2f((u16)(u.y&0xFFFFu)); a[3] += qv*b2f((u16)(u.y>>16));
  a[4] += qv*b2f((u16)(u.z&0xFFFFu)); a[5] += qv*b2f((u16)(u.z>>16));
  a[6] += qv*b2f((u16)(u.w&0xFFFFu)); a[7] += qv*b2f((u16)(u.w>>16));
}

// ---------------- k_pre: tables + 3x weight cvt + x transpose (5 launches -> 1) ----------------
__global__ __launch_bounds__(256) void k_pre(const float* __restrict__ x, const float* __restrict__ qkvw,
                                             const float* __restrict__ w1, const float* __restrict__ w2,
                                             float* __restrict__ W127, float* __restrict__ W64,
                                             u16* __restrict__ wqb, u16* __restrict__ w1b,
                                             u16* __restrict__ w2b, u16* __restrict__ xq){
  int blk = blockIdx.x, tid = threadIdx.x;
  if (blk == 0){
    int i = tid;
    if (i < 33){
      const float inv = 127.0f/33.0f;
      float xx = ((float)i + 0.5f)*inv - 0.5f;
      float s = 0.f;
      for (int j=0;j<127;++j){ float w = 1.0f - fabsf((float)j - xx)/inv; w = fmaxf(w,0.f); W127[i*127+j]=w; s+=w; }
      float r = 1.0f/s;
      for (int j=0;j<127;++j) W127[i*127+j] *= r;
    } else if (i < 66){
      int ii = i-33;
      const float inv = 64.0f/33.0f;
      float xx = ((float)ii + 0.5f)*inv - 0.5f;
      float s=0.f;
      for (int j=0;j<64;++j){ float w = 1.0f - fabsf((float)j - xx)/inv; w=fmaxf(w,0.f); W64[ii*64+j]=w; s+=w; }
      float r=1.0f/s;
      for (int j=0;j<64;++j) W64[ii*64+j]*=r;
    }
  } else if (blk < 129){
    int id = (blk-1)*256 + tid;
    if (id < 32768) wqb[id] = f2b(qkvw[id]);
  } else if (blk < 385){
    int id = (blk-129)*256 + tid;
    if (id < 65536) w1b[id] = f2b(w1[id]);
  } else if (blk < 641){
    int id = (blk-385)*256 + tid;
    if (id < 65536) w2b[id] = f2b(w2[id]);
  } else {
    __shared__ float T[128][66];
    int bx = blk - 641;
    int n = bx>>6, h = bx&63;
    for (int e=tid;e<8192;e+=256){
      int c = e>>6, w = e&63;                  // 64-float contiguous reads per c
      T[c][w] = x[(((size_t)(n*128+c))*64 + h)*64 + w];
    }
    __syncthreads();
    for (int e=tid;e<8192;e+=256){
      int w = e>>7, c = e&127;                 // 256B contiguous u16 stores per w
      xq[(((size_t)(n*64+w))*64 + h)*128 + c] = f2b(T[c][w]);
    }
  }
}

// ---------------- k_qkvp1: QKV MFMA GEMM (blk<512) + pos1 (blk 512..1035) ----------------
__global__ __launch_bounds__(256) void k_qkvp1(const u16* __restrict__ xq, const u16* __restrict__ wqb,
                                               u16* __restrict__ qkvT, float2* __restrict__ part,
                                               const float* __restrict__ base, const float* __restrict__ W127,
                                               float* __restrict__ tmp){
  if (blockIdx.x < 512){
    int b = blockIdx.x;
    int tid = threadIdx.x;
    int wv = tid>>6, l = tid&63;
    int wn = wv*64;
    int lr = l&15, lq = l>>4;
    __shared__ u16 As[64*40];
    __shared__ u16 Bs[256*40];
    f32x4 acc[4][4];
    #pragma unroll
    for (int mi=0;mi<4;++mi)
      #pragma unroll
      for (int ni=0;ni<4;++ni) acc[mi][ni] = (f32x4){0.f,0.f,0.f,0.f};
    const u16* Ag = xq + (size_t)b*8192;      // [64][128]
    const u16* Bg = wqb;                       // [256][128]
    for (int ks=0; ks<128; ks+=32){
      __syncthreads();
      { int e = tid; int row = e>>2, q = e&3;
        *(uint4*)&As[row*40 + q*8] = *(const uint4*)&Ag[(size_t)row*128 + ks + q*8]; }
      #pragma unroll
      for (int p=0;p<4;++p){
        int e = tid + p*256; int row = e>>2, q = e&3;
        *(uint4*)&Bs[row*40 + q*8] = *(const uint4*)&Bg[(size_t)row*128 + ks + q*8];
      }
      __syncthreads();
      bf16x8 af[4], bfr[4];
      #pragma unroll
      for (int mi=0;mi<4;++mi) af[mi] = *(const bf16x8*)&As[(mi*16 + lr)*40 + lq*8];
      #pragma unroll
      for (int ni=0;ni<4;++ni) bfr[ni] = *(const bf16x8*)&Bs[(wn + ni*16 + lr)*40 + lq*8];
      #pragma unroll
      for (int mi=0;mi<4;++mi)
        #pragma unroll
        for (int ni=0;ni<4;++ni)
          acc[mi][ni] = __builtin_amdgcn_mfma_f32_16x16x32_bf16(af[mi], bfr[ni], acc[mi][ni], 0,0,0);
    }
    // epilogue: bf16 C store + per-channel (o) fp32 partial sums over l (this b)
    float cs[4] = {0.f,0.f,0.f,0.f}, cq[4] = {0.f,0.f,0.f,0.f};
    u16* ob = qkvT + (size_t)b*16384;
    #pragma unroll
    for (int mi=0;mi<4;++mi)
      #pragma unroll
      for (int r=0;r<4;++r){
        int row = mi*16 + lq*4 + r;
        #pragma unroll
        for (int ni=0;ni<4;++ni){
          float v = acc[mi][ni][r];
          ob[(size_t)row*256 + wn + ni*16 + lr] = f2b(v);
          cs[ni] += v; cq[ni] += v*v;
        }
      }
    #pragma unroll
    for (int ni=0;ni<4;++ni){
      cs[ni] += __shfl_xor(cs[ni], 16); cs[ni] += __shfl_xor(cs[ni], 32);
      cq[ni] += __shfl_xor(cq[ni], 16); cq[ni] += __shfl_xor(cq[ni], 32);
    }
    if (lq == 0){
      #pragma unroll
      for (int ni=0;ni<4;++ni)
        part[(size_t)(wn + ni*16 + lr)*512 + b] = make_float2(cs[ni], cq[ni]);
    }
  } else {
    int id = (blockIdx.x-512)*256 + threadIdx.x;
    if (id >= 32*33*127) return;
    int c = id / 4191; int r = id - c*4191; int i = r / 127; int xx = r - i*127;
    const float* wr = W127 + i*127;
    const float* bc = base + c*16129 + xx;
    float a=0.f;
    for (int y=0;y<127;++y) a += wr[y]*bc[y*127];
    tmp[id] = a;
  }
}

// ---------------- k_st2p2: qkv BN stats (blk<8) + pos2 (blk 8..144) ----------------
__global__ __launch_bounds__(256) void k_st2p2(const float2* __restrict__ part, const float* __restrict__ g,
                                               const float* __restrict__ bta, float2* __restrict__ st,
                                               const float* __restrict__ tmp, const float* __restrict__ W127,
                                               float* __restrict__ pos){
  if (blockIdx.x < 8){
    int t = threadIdx.x;
    int chL = t>>3, seg = t&7;
    int ch = blockIdx.x*32 + chL;
    float s=0.f, s2=0.f;
    const float2* p = part + (size_t)ch*512 + seg*64;
    #pragma unroll 8
    for (int r=0;r<64;++r){ float2 q = p[r]; s+=q.x; s2+=q.y; }
    __shared__ float A[32][9], Bq[32][9];
    A[chL][seg]=s; Bq[chL][seg]=s2; __syncthreads();
    if (seg==0){
      #pragma unroll
      for (int k=1;k<8;++k){ s += A[chL][k]; s2 += Bq[chL][k]; }
      float m = s*(1.0f/32768.0f);
      float var = s2*(1.0f/32768.0f) - m*m;
      float sc = g[ch]/sqrtf(var + EPSV);
      st[ch] = make_float2(sc, bta[ch] - m*sc);
    }
  } else {
    int id = (blockIdx.x-8)*256 + threadIdx.x;
    if (id >= 32*33*33) return;
    int c = id / 1089; int r = id - c*1089; int i = r / 33; int j = r - i*33;
    const float* wr = W127 + j*127;
    const float* tc = tmp + c*4191 + i*127;
    float a=0.f;
    for (int xx=0;xx<127;++xx) a += wr[xx]*tc[xx];
    pos[id] = a;
  }
}

// ---------------- k_stats2: generic 256-ch x 512-row partial reducer (used for so stats too) ----------------
__global__ void k_stats2(const float2* __restrict__ part, const float* __restrict__ g,
                         const float* __restrict__ bta, float2* __restrict__ st){
  int t = threadIdx.x;
  int chL = t>>3, seg = t&7;
  int ch = blockIdx.x*32 + chL;
  float s=0.f, s2=0.f;
  const float2* p = part + (size_t)ch*512 + seg*64;
  #pragma unroll 8
  for (int r=0;r<64;++r){ float2 q = p[r]; s+=q.x; s2+=q.y; }
  __shared__ float A[32][9], Bq[32][9];
  A[chL][seg]=s; Bq[chL][seg]=s2; __syncthreads();
  if (seg==0){
    #pragma unroll
    for (int k=1;k<8;++k){ s += A[chL][k]; s2 += Bq[chL][k]; }
    float m = s*(1.0f/32768.0f);
    float var = s2*(1.0f/32768.0f) - m*m;
    float sc = g[ch]/sqrtf(var + EPSV);
    st[ch] = make_float2(sc, bta[ch] - m*sc);
  }
}

// ---------------- k_qkvr_kv: qkvr (blk<512) + keT (512..546) + veP (547..678) ----------------
__global__ __launch_bounds__(256) void k_qkvr_kv(const u16* __restrict__ qkvT, const float* __restrict__ W64,
                                                 const float2* __restrict__ st, u16* __restrict__ qkvrT,
                                                 const float* __restrict__ pos, float* __restrict__ keT,
                                                 u16* __restrict__ VeP){
  int blk = blockIdx.x;
  if (blk < 512){
    int b = blk, ch = threadIdx.x;
    const u16* base = qkvT + (size_t)b*16384 + ch;
    float xr[64];
    #pragma unroll
    for (int t=0;t<64;++t) xr[t] = b2f(base[t*256]);
    float2 sb = st[ch];
    u16* ob = qkvrT + (size_t)b*8448 + ch;
    for (int i=0;i<33;++i){
      const float4* wr = (const float4*)(W64 + i*64);
      float a = 0.f;
      #pragma unroll
      for (int q=0;q<16;++q){
        float4 w4 = wr[q];
        a += w4.x*xr[4*q] + w4.y*xr[4*q+1] + w4.z*xr[4*q+2] + w4.w*xr[4*q+3];
      }
      ob[i*256] = f2b(a*sb.x + sb.y);
    }
  } else if (blk < 547){
    int id = (blk-512)*256 + threadIdx.x;
    if (id >= 8712) return;
    int c = id / 1089; int r = id - c*1089; int i = r / 33; int j = r - i*33;
    keT[id] = pos[(8+c)*1089 + j*33 + i];
  } else {
    int id = (blk-547)*256 + threadIdx.x;
    if (id >= 33792) return;
    int c = id & 15;
    int i = (id >> 4) & 63;
    int k = id >> 10;
    int i0; float fi; upfac(i, i0, fi);
    const float* P = pos + (16+c)*1089;
    VeP[id] = f2b((1.f-fi)*P[i0*33 + k] + fi*P[(i0+1)*33 + k]);
  }
}

// ---------------- sim = concat([qk, qr, kr]) bf16 + per-block stats partials (fp32) ----------------
__global__ __launch_bounds__(256) void k_sim(const u16* __restrict__ qkvrT, const float* __restrict__ pos,
                                             const float* __restrict__ keT,
                                             u16* __restrict__ sim, float* __restrict__ part6){
  int b = blockIdx.x, g = blockIdx.y;
  __shared__ float lqa[264], lka[264];
  int tid = threadIdx.x;
  for (int e=tid;e<528;e+=256){
    int half = (e < 264) ? 0 : 1;
    int e2 = e - half*264;
    int c = e2/33, i = e2 - c*33;
    float v = b2f(qkvrT[(size_t)b*8448 + i*256 + (g*32 + half*8 + c)]);
    if (half==0) lqa[e2]=v; else lka[e2]=v;
  }
  __syncthreads();
  float sqk=0.f,qqk=0.f,sqr=0.f,qqr=0.f,skr=0.f,qkr=0.f;
  for (int p=tid;p<1089;p+=256){
    int i = p/33, j = p - i*33;
    float qk=0.f, qr=0.f, kr=0.f;
    #pragma unroll
    for (int c=0;c<8;++c){
      float qa_ = lqa[c*33+i];
      float ka_ = lka[c*33+j];
      qk += qa_*ka_;
      qr += qa_*pos[c*1089 + i*33 + j];
      kr += ka_*keT[c*1089 + i*33 + j];
    }
    sim[(size_t)(b*24 + g)*1089 + p] = f2b(qk);
    sim[(size_t)(b*24 + 8 + g)*1089 + p] = f2b(qr);
    sim[(size_t)(b*24 + 16 + g)*1089 + p] = f2b(kr);
    sqk+=qk; qqk+=qk*qk; sqr+=qr; qqr+=qr*qr; skr+=kr; qkr+=kr*kr;
  }
  __shared__ float red[6][256];
  red[0][tid]=sqk; red[1][tid]=qqk; red[2][tid]=sqr;
  red[3][tid]=qqr; red[4][tid]=skr; red[5][tid]=qkr;
  __syncthreads();
  for (int o=128;o>0;o>>=1){
    if (tid<o){
      #pragma unroll
      for (int c=0;c<6;++c) red[c][tid]+=red[c][tid+o];
    }
    __syncthreads();
  }
  if (tid<6) part6[(size_t)(b*8+g)*6 + tid] = red[tid][0];
}

// ---------------- simst from part6 ----------------
__global__ void k_sstB(const float* __restrict__ part6, const float* __restrict__ g,
                       const float* __restrict__ bta, float2* __restrict__ st){
  int nb = threadIdx.x;
  if (nb >= 192) return;
  int n = nb/24, ch = nb - n*24;
  int t3 = ch>>3, gg = ch&7;
  float s=0.f, s2=0.f;
  for (int w=0; w<64; ++w){
    const float* p = part6 + (size_t)((n*64+w)*8 + gg)*6 + 2*t3;
    s += p[0]; s2 += p[1];
  }
  float m = s*(1.0f/69696.0f);
  float var = s2*(1.0f/69696.0f) - m*m;
  float sc = g[ch]/sqrtf(var + EPSV);
  st[nb] = make_float2(sc, bta[ch] - m*sc);
}

// ---------------- fused attention + so-stats partials (replaces separate k_sost1) --------------
// Each wave owns 16 output channels (ch = g*32 + half*16 + 2c{+1}) x 64 i-lanes for one b.
// Partials computed from the bf16-ROUNDED store values (bit-compatible with the old
// so re-read); 6-step shfl_xor butterfly, lane 0 writes part2[ch*512+b].
__global__ __launch_bounds__(256,4) void k_attn(const u16* __restrict__ sim, const float2* __restrict__ simst,
                                                const u16* __restrict__ qkvrT, const u16* __restrict__ veP,
                                                u16* __restrict__ so, float2* __restrict__ part2){
  int tid = threadIdx.x;
  int wv = tid >> 6;
  int i  = tid & 63;
  int pr   = wv >> 1;      // bg slot within block
  int half = wv & 1;       // channel half: 0 -> c 0..7, 1 -> c 8..15
  __shared__ float  S[2][1092];
  __shared__ float4 Va[2][132];
  // cooperative staging of 2 bg tiles
  #pragma unroll
  for (int p2=0;p2<2;++p2){
    int bg2 = blockIdx.x*2 + p2;
    int b2 = bg2>>3, g2 = bg2&7, n2 = b2>>6;
    float2 sb0 = simst[n2*24 + g2], sb1 = simst[n2*24 + 8 + g2], sb2 = simst[n2*24 + 16 + g2];
    float badd = sb0.y + sb1.y + sb2.y;
    const u16* s0 = sim + ((size_t)b2*24 + g2)*1089;
    for (int e=tid;e<1089;e+=256)
      S[p2][e] = b2f(s0[e])*sb0.x + b2f(s0[e+8712])*sb1.x + b2f(s0[e+17424])*sb2.x + badd;
    for (int e=tid;e<132;e+=256){
      int j = e>>2, cq = e&3;
      const u16* qp = qkvrT + (size_t)b2*8448 + j*256 + g2*32 + 16 + cq*4;
      uint2 u = *(const uint2*)qp;
      Va[p2][e] = make_float4(b2f((u16)(u.x&0xFFFFu)), b2f((u16)(u.x>>16)),
                              b2f((u16)(u.y&0xFFFFu)), b2f((u16)(u.y>>16)));
    }
  }
  __syncthreads();

  int bg = blockIdx.x*2 + pr;
  int b = bg>>3, g = bg&7;

  // phase A: i-lerped score row, exp, fold into qk[33] (duplicated across the wave pair)
  int i0; float fi; upfac(i, i0, fi);
  const float* R0 = S[pr] + i0*33;
  float rowv[33];
  #pragma unroll
  for (int k=0;k<33;++k) rowv[k] = R0[k] + fi*(R0[k+33] - R0[k]);
  float qk[33];
  #pragma unroll
  for (int k=0;k<33;++k) qk[k] = 0.f;
  float s = 0.f;
  #pragma unroll
  for (int j=0;j<64;++j){
    float fj = UT.fj[j]; int j0 = UT.j0[j];
    float v = rowv[j0] + fj*(rowv[j0+1] - rowv[j0]);
    float e = __expf(v);
    s += e;
    qk[j0]   += e*(1.f-fj);
    qk[j0+1] += e*fj;
  }
  float inv = 1.f/s;

  // phase B: this wave's 8-channel half; chunk-of-11 loads (compiler schedules ~3 in flight)
  float av[8], ae[8];
  #pragma unroll
  for (int c=0;c<8;++c){ av[c]=0.f; ae[c]=0.f; }
  const uint4* vp  = (const uint4*)veP + (size_t)i*2 + half;   // one uint4 (8 ch) per k
  const float4* va4 = &Va[pr][half*2];                          // two float4 (8 ch) per k
  #pragma unroll
  for (int kc=0; kc<33; kc+=11){
    uint4 e0 = vp[(kc+0)*128],  e1 = vp[(kc+1)*128],  e2 = vp[(kc+2)*128];
    uint4 e3 = vp[(kc+3)*128],  e4 = vp[(kc+4)*128],  e5 = vp[(kc+5)*128];
    uint4 e6 = vp[(kc+6)*128],  e7 = vp[(kc+7)*128],  e8 = vp[(kc+8)*128];
    uint4 e9 = vp[(kc+9)*128],  e10= vp[(kc+10)*128];
    // LDS-fed work covers global latency
    #pragma unroll
    for (int t2=0;t2<11;++t2)
      fma8(av, qk[kc+t2], va4[(kc+t2)*4+0], va4[(kc+t2)*4+1]);
    // consume globals (unpack bf16)
    fma8h(ae, qk[kc+0], e0);  fma8h(ae, qk[kc+1], e1);  fma8h(ae, qk[kc+2], e2);
    fma8h(ae, qk[kc+3], e3);  fma8h(ae, qk[kc+4], e4);  fma8h(ae, qk[kc+5], e5);
    fma8h(ae, qk[kc+6], e6);  fma8h(ae, qk[kc+7], e7);  fma8h(ae, qk[kc+8], e8);
    fma8h(ae, qk[kc+9], e9);  fma8h(ae, qk[kc+10], e10);
  }
  u16* ob = so + (size_t)b*16384 + g*2048 + (half*8)*128;
  float ps[16], pq[16];
  #pragma unroll
  for (int c=0;c<8;++c){
    u16 ra = f2b(av[c]*inv), re = f2b(ae[c]*inv);
    ob[c*128 + i]      = ra;
    ob[c*128 + 64 + i] = re;
    float va_ = b2f(ra), ve_ = b2f(re);
    ps[2*c]   = va_; pq[2*c]   = va_*va_;
    ps[2*c+1] = ve_; pq[2*c+1] = ve_*ve_;
  }
  // 64-lane butterfly reduce of 16 channel sums + sq-sums
  #pragma unroll
  for (int c=0;c<16;++c){
    #pragma unroll
    for (int off=32; off; off>>=1){
      ps[c] += __shfl_xor(ps[c], off);
      pq[c] += __shfl_xor(pq[c], off);
    }
  }
  if (i == 0){
    int chb = g*32 + half*16;
    #pragma unroll
    for (int c=0;c<16;++c)
      part2[(size_t)(chb+c)*512 + b] = make_float2(ps[c], pq[c]);
  }
}

// ---------------- BN(so) + pair-sum + transpose -> o + xo-stats partials ----------------
__global__ __launch_bounds__(256) void k_o(const u16* __restrict__ so, const float2* __restrict__ st,
                                           float* __restrict__ o, float* __restrict__ opart){
  __shared__ float T[64][65];
  __shared__ float R1[256], R2[256];
  int n = blockIdx.x>>7, oc = blockIdx.x&127;
  int tid = threadIdx.x;
  float2 s0 = st[2*oc], s1 = st[2*oc+1];
  float badd = s0.y + s1.y;
  for (int e=tid;e<4096;e+=256){
    int w = e>>6, h = e&63;                  // lanes along h: contiguous so reads
    const u16* sb = so + (size_t)(n*64+w)*16384 + (2*oc)*64;
    T[w][h] = b2f(sb[h])*s0.x + b2f(sb[64+h])*s1.x + badd;
  }
  __syncthreads();
  for (int e=tid;e<4096;e+=256){
    int h = e>>6, w = e&63;                  // lanes along w: contiguous o writes
    o[(((size_t)(n*128+oc))*64 + h)*64 + w] = T[w][h];
  }
  // ---- stats partials (T intact) ----
  float fs=0.f, fq=0.f;
  for (int e=tid;e<4096;e+=256){ float v = T[e>>6][e&63]; fs+=v; fq+=v*v; }
  R1[tid]=fs; R2[tid]=fq; __syncthreads();
  for (int o2=128;o2>0;o2>>=1){ if(tid<o2){ R1[tid]+=R1[tid+o2]; R2[tid]+=R2[tid+o2]; } __syncthreads(); }
  float* rec = opart + (size_t)(n*128+oc)*18;
  if (tid==0){ rec[0]=R1[0]; rec[1]=R2[0]; }
  if (tid < 64){
    int l = tid;                             // wave 0, lane l = h index
    float c0=T[0][l], c1=T[1][l], c62=T[62][l], c63=T[63][l];
    float d0=c0*c0, d1=c1*c1, d62=c62*c62, d63=c63*c63;
    #pragma unroll
    for (int off=32; off; off>>=1){
      c0+=__shfl_xor(c0,off); c1+=__shfl_xor(c1,off);
      c62+=__shfl_xor(c62,off); c63+=__shfl_xor(c63,off);
      d0+=__shfl_xor(d0,off); d1+=__shfl_xor(d1,off);
      d62+=__shfl_xor(d62,off); d63+=__shfl_xor(d63,off);
    }
    if (l==0){
      rec[2]=c0; rec[3]=d0; rec[4]=c1; rec[5]=d1;
      rec[6]=c62; rec[7]=d62; rec[8]=c63; rec[9]=d63;
    }
  } else if (tid < 128){
    int l = tid & 63;                        // wave 1, lane l = w index
    float r0=T[l][0], r1=T[l][1], r62=T[l][62], r63=T[l][63];
    float e0=r0*r0, e1=r1*r1, e62=r62*r62, e63=r63*r63;
    #pragma unroll
    for (int off=32; off; off>>=1){
      r0+=__shfl_xor(r0,off); r1+=__shfl_xor(r1,off);
      r62+=__shfl_xor(r62,off); r63+=__shfl_xor(r63,off);
      e0+=__shfl_xor(e0,off); e1+=__shfl_xor(e1,off);
      e62+=__shfl_xor(e62,off); e63+=__shfl_xor(e63,off);
    }
    if (l==0){
      rec[10]=r0; rec[11]=e0; rec[12]=r1; rec[13]=e1;
      rec[14]=r62; rec[15]=e62; rec[16]=r63; rec[17]=e63;
    }
  }
}

// ---------------- xo instance-norm stats from k_o plane records ----------------
__global__ void k_instB(const float* __restrict__ opart, const float* __restrict__ g,
                        const float* __restrict__ bta, float2* __restrict__ st){
  int nb = blockIdx.x*256 + threadIdx.x;
  if (nb >= 1024) return;
  int n = nb>>7, c = nb&127;
  float s, q;
  if (c >= 40){
    const float* r = opart + (size_t)(n*128+c)*18;
    s = r[0]; q = r[1];
  } else {
    int grp = c/10, cc = c - grp*10;
    const float* r = opart + (size_t)(n*128+cc)*18;
    if (grp==0){ s = r[0]-r[6]-r[8];   q = r[1]-r[7]-r[9];  }
    else if (grp==1){ s = r[0]-r[2]-r[4];   q = r[1]-r[3]-r[5];  }
    else if (grp==2){ s = r[0]-r[14]-r[16]; q = r[1]-r[15]-r[17];}
    else            { s = r[0]-r[10]-r[12]; q = r[1]-r[11]-r[13];}
  }
  float m = s*(1.0f/4096.0f);
  float var = q*(1.0f/4096.0f) - m*m;
  float sc = g[c]/sqrtf(var + EPSV);
  st[nb] = make_float2(sc, bta[c] - m*sc);
}

// ---------------- spatial block ----------------
__device__ __forceinline__ float xo_val(const float* __restrict__ o, int n, int c, int h, int w){
  if (c >= 40) return o[((n*128 + c)*64 + h)*64 + w];
  int grp = c / 10;
  int cc = c - grp*10;
  int base = (n*128 + cc)*64;
  if (grp==0) return (w>=2) ? o[(base + h)*64 + (w-2)] : 0.f;
  if (grp==1) return (w<62) ? o[(base + h)*64 + (w+2)] : 0.f;
  if (grp==2) return (h>=2) ? o[(base + (h-2))*64 + w] : 0.f;
  return (h<62) ? o[(base + (h+2))*64 + w] : 0.f;
}

// ---------------- fused: instance-norm(xo) + transpose -> xnT bf16 [n][hw][c] ----------------
__global__ __launch_bounds__(256) void k_xnt(const float* __restrict__ o, const float2* __restrict__ st,
                                             u16* __restrict__ xnT){
  __shared__ float T[64][65];
  int h = blockIdx.x&63, c0 = ((blockIdx.x>>6)&1)*64, n = blockIdx.x>>7;
  int tid = threadIdx.x;
  for (int e=tid;e<4096;e+=256){
    int cL = e>>6, w = e&63;                 // lanes along w: coalesced xo_val reads
    float2 sb = st[n*128 + c0+cL];           // wave-uniform
    T[cL][w] = xo_val(o, n, c0+cL, h, w)*sb.x + sb.y;
  }
  __syncthreads();
  for (int e=tid;e<4096;e+=256){
    int wL = e>>6, cL = e&63;                // lanes along c: 128B contiguous stores
    xnT[((size_t)(n*4096 + h*64 + wL))*128 + c0 + cL] = f2b(T[cL][wL]);
  }
}

// ---------------- mlp1: D[128 hw][64 co] per block, 4 waves (2x2 of 64x32); grid (32,8,8)=2048 ----
__global__ __launch_bounds__(256) void k_mlp1(const u16* __restrict__ xnT, const u16* __restrict__ w1b,
                                              u16* __restrict__ h1T){
  int hw0 = blockIdx.x*128, co0 = blockIdx.y*64, n = blockIdx.z;
  int tid = threadIdx.x;
  int wv = tid>>6, l = tid&63;
  int wm = (wv>>1)*64, wn = (wv&1)*32;
  int lr = l&15, lq = l>>4;
  __shared__ u16 As[128*40];
  __shared__ u16 Bs[64*40];
  f32x4 acc[4][2];
  #pragma unroll
  for (int mi=0;mi<4;++mi)
    #pragma unroll
    for (int ni=0;ni<2;++ni) acc[mi][ni] = (f32x4){0.f,0.f,0.f,0.f};
  const u16* Ag = xnT + ((size_t)(n*4096 + hw0))*128;
  const u16* Bg = w1b + (size_t)co0*128;
  for (int ks=0; ks<128; ks+=32){
    __syncthreads();
    #pragma unroll
    for (int p=0;p<2;++p){
      int e = tid + p*256; int row = e>>2, q = e&3;
      *(uint4*)&As[row*40 + q*8] = *(const uint4*)&Ag[(size_t)row*128 + ks + q*8];
    }
    { int e = tid; int row = e>>2, q = e&3;
      *(uint4*)&Bs[row*40 + q*8] = *(const uint4*)&Bg[(size_t)row*128 + ks + q*8]; }
    __syncthreads();
    bf16x8 af[4], bfr[2];
    #pragma unroll
    for (int mi=0;mi<4;++mi) af[mi] = *(const bf16x8*)&As[(wm + mi*16 + lr)*40 + lq*8];
    #pragma unroll
    for (int ni=0;ni<2;++ni) bfr[ni] = *(const bf16x8*)&Bs[(wn + ni*16 + lr)*40 + lq*8];
    #pragma unroll
    for (int mi=0;mi<4;++mi)
      #pragma unroll
      for (int ni=0;ni<2;++ni)
        acc[mi][ni] = __builtin_amdgcn_mfma_f32_16x16x32_bf16(af[mi], bfr[ni], acc[mi][ni], 0,0,0);
  }
  u16* ob = h1T + ((size_t)(n*4096 + hw0 + wm))*512 + co0 + wn;
  #pragma unroll
  for (int mi=0;mi<4;++mi)
    #pragma unroll
    for (int r=0;r<4;++r){
      int row = mi*16 + lq*4 + r;
      #pragma unroll
      for (int ni=0;ni<2;++ni){
        float v = acc[mi][ni][r];
        ob[(size_t)row*512 + ni*16 + lr] = f2b(gelu_f(v));
      }
    }
}

// ---------------- mlp2: split-K(2) + hw-tile 64; grid (64,2,8)=1024, atomicAdd commit ----
__global__ __launch_bounds__(256) void k_mlp2(const u16* __restrict__ w2b, const u16* __restrict__ h1T,
                                              float* __restrict__ out){
  int hw0 = blockIdx.x*64, n = blockIdx.z;
  int ks0 = blockIdx.y*256;                 // K half: [ks0, ks0+256)
  int tid = threadIdx.x;
  int wv = tid>>6, l = tid&63;
  int wm = (wv>>1)*64, wn = (wv&1)*32;      // wm: co offset, wn: hw offset
  int lr = l&15, lq = l>>4;
  __shared__ u16 As[128*40];
  __shared__ u16 Bs[64*40];
  f32x4 acc[4][2];
  #pragma unroll
  for (int mi=0;mi<4;++mi)
    #pragma unroll
    for (int ni=0;ni<2;++ni) acc[mi][ni] = (f32x4){0.f,0.f,0.f,0.f};
  const u16* Ag = w2b;
  const u16* Bg = h1T + ((size_t)(n*4096 + hw0))*512;
  for (int ks=ks0; ks<ks0+256; ks+=32){
    __syncthreads();
    #pragma unroll
    for (int p=0;p<2;++p){
      int e = tid + p*256; int row = e>>2, q = e&3;
      *(uint4*)&As[row*40 + q*8] = *(const uint4*)&Ag[(size_t)row*512 + ks + q*8];
    }
    { int e = tid; int row = e>>2, q = e&3;
      *(uint4*)&Bs[row*40 + q*8] = *(const uint4*)&Bg[(size_t)row*512 + ks + q*8]; }
    __syncthreads();
    bf16x8 af[4], bfr[2];
    #pragma unroll
    for (int mi=0;mi<4;++mi) af[mi] = *(const bf16x8*)&As[(wm + mi*16 + lr)*40 + lq*8];
    #pragma unroll
    for (int ni=0;ni<2;++ni) bfr[ni] = *(const bf16x8*)&Bs[(wn + ni*16 + lr)*40 + lq*8];
    #pragma unroll
    for (int mi=0;mi<4;++mi)
      #pragma unroll
      for (int ni=0;ni<2;++ni)
        acc[mi][ni] = __builtin_amdgcn_mfma_f32_16x16x32_bf16(af[mi], bfr[ni], acc[mi][ni], 0,0,0);
  }
  #pragma unroll
  for (int mi=0;mi<4;++mi)
    #pragma unroll
    for (int r=0;r<4;++r){
      int cout = wm + mi*16 + lq*4 + r;
      #pragma unroll
      for (int ni=0;ni<2;++ni){
        size_t idx = ((size_t)(n*128 + cout))*4096 + hw0 + wn + ni*16 + lr;
        atomicAdd(&out[idx], acc[mi][ni][r]);
      }
    }
}

extern "C" void kernel_launch(void* const* d_in, const int* in_sizes, int n_in,
                              void* d_out, int out_size, void* d_ws, size_t ws_size,
                              hipStream_t stream) {
  (void)in_sizes; (void)n_in; (void)out_size; (void)ws_size;
  const float* x       = (const float*)d_in[0];
  const float* qkvw    = (const float*)d_in[1];
  const float* bng     = (const float*)d_in[2];
  const float* bnb     = (const float*)d_in[3];
  const float* baserel = (const float*)d_in[4];
  const float* simg    = (const float*)d_in[5];
  const float* simb    = (const float*)d_in[6];
  const float* outg    = (const float*)d_in[7];
  const float* outb    = (const float*)d_in[8];
  const float* ing     = (const float*)d_in[9];
  const float* inb     = (const float*)d_in[10];
  const float* w1      = (const float*)d_in[11];
  const float* w2      = (const float*)d_in[12];

  float* ws = (float*)d_ws;
  float*  W127  = ws + F_W127;
  float*  W64   = ws + F_W64;
  float2* qkvst = (float2*)(ws + F_QKVST);
  float2* simst = (float2*)(ws + F_SIMST);
  float2* sost  = (float2*)(ws + F_SOST);
  float2* inst  = (float2*)(ws + F_INST);
  float*  postmp= ws + F_POSTMP;
  float*  pos   = ws + F_POS;
  u16*    qkvT  = (u16*)(ws + F_QKV);
  u16*    qkvrT = (u16*)(ws + F_QKVR);
  u16*    sim   = (u16*)(ws + F_SIM);
  float*  part6 = ws + F_PART6;
  float2* part2 = (float2*)(ws + F_PART6);   // so-stats partials (after part6 dead at k_sstB)
  float2* bnp   = (float2*)(ws + F_BNP2);    // qkv BN partials (k_qkvp1..k_st2p2)
  float*  opart = ws + F_BNP2;               // plane stat records (k_o..k_instB); bnp dead by then
  u16*    wqb   = (u16*)(ws + F_WQB);        // bf16 qkv weight
  u16*    veP   = (u16*)(ws + F_VEH);
  u16*    xnT   = (u16*)(ws + F_XNT);
  float*  keT   = ws + F_KET;
  u16*    so    = (u16*)(ws + F_SO);
  u16*    xq    = (u16*)(ws + F_XQ);
  u16*    h1T   = (u16*)(ws + F_H1);
  u16*    w1b   = (u16*)(ws + F_W1B);        // in PART6 dead sub-range (>= +1048576)
  u16*    w2b   = (u16*)(ws + F_W2B);
  float*  out   = (float*)d_out;

  k_pre     <<<dim3(1153),     dim3(256), 0, stream>>>(x, qkvw, w1, w2, W127, W64, wqb, w1b, w2b, xq);
  k_qkvp1   <<<dim3(1036),     dim3(256), 0, stream>>>(xq, wqb, qkvT, bnp, baserel, W127, postmp);
  k_st2p2   <<<dim3(145),      dim3(256), 0, stream>>>(bnp, bng, bnb, qkvst, postmp, W127, pos);
  k_qkvr_kv <<<dim3(679),      dim3(256), 0, stream>>>(qkvT, W64, qkvst, qkvrT, pos, keT, veP);
  k_sim     <<<dim3(512,8),    dim3(256), 0, stream>>>(qkvrT, pos, keT, sim, part6);
  k_sstB    <<<dim3(1),        dim3(192), 0, stream>>>(part6, simg, simb, simst);
  k_attn    <<<dim3(2048),     dim3(256), 0, stream>>>(sim, simst, qkvrT, veP, so, part2);
  k_stats2  <<<dim3(8),        dim3(256), 0, stream>>>(part2, outg, outb, sost);
  k_o       <<<dim3(1024),     dim3(256), 0, stream>>>(so, sost, out, opart);
  k_instB   <<<dim3(4),        dim3(256), 0, stream>>>(opart, ing, inb, inst);
  k_xnt     <<<dim3(1024),     dim3(256), 0, stream>>>(out, inst, xnT);
  k_mlp1    <<<dim3(32,8,8),   dim3(256), 0, stream>>>(xnT, w1b, h1T);
  k_mlp2    <<<dim3(64,2,8),   dim3(256), 0, stream>>>(w2b, h1T, out);
}

// Round 27
// 211.053 us; speedup vs baseline: 1.0430x; 1.0430x over previous
//
#include <hip/hip_runtime.h>
#include <math.h>

// Problem constants: N=8, C=128, H=64, W=64, B=N*W=512, ADJ=33, G=8, GP=16
constexpr float EPSV = 1e-5f;
typedef unsigned short u16;
using bf16x8 = __attribute__((ext_vector_type(8))) short;
using f32x4  = __attribute__((ext_vector_type(4))) float;

// ---------------- workspace layout (offsets in floats) ----------------
constexpr size_t F_W127  = 0;
constexpr size_t F_W64   = F_W127 + 4224;
constexpr size_t F_QKVST = F_W64  + 2112;
constexpr size_t F_SIMST = F_QKVST+ 512;
constexpr size_t F_SOST  = F_SIMST+ 384;
constexpr size_t F_INST  = F_SOST + 512;
constexpr size_t F_POSTMP= F_INST + 2048;          // 134112 (pos1 tmp; dead after pos2)
constexpr size_t F_POS   = F_POSTMP + 134112;      // 34848
constexpr size_t F_QKV   = F_POS  + 34848;         // qkvT u16 [512][64][256] (alias: SO u16 later)
constexpr size_t F_QKVR  = F_QKV  + 8388608;       // qkvrT u16 [512][33][256]
constexpr size_t F_SIM   = F_QKVR + 4325376;       // sim u16 13381632 elems (alias: XQ early, h1T later)
constexpr size_t F_PART6 = F_SIM  + 13381632;      // region: part6 / sopart / bnp / opart / wqb / w1b / w2b
constexpr size_t F_VEH   = F_PART6 + 4460544;      // VeP u16 33792 elems
constexpr size_t F_XNT   = F_VEH  + 33792;         // xnT bf16 = 2097152 f
constexpr size_t F_KET   = F_XNT  + 2097152;       // keT 8712
constexpr size_t F_SO    = F_QKV;                  // so u16 [512][256][64] (after qkvT dead)
constexpr size_t F_XQ    = F_SIM;                  // xq bf16 [512][64][128] (dies before k_sim)
constexpr size_t F_BNP2  = F_PART6 + 262144;       // qkv BN partials; then opart (k_o..k_instB)
constexpr size_t F_WQB   = F_PART6 + 524288;       // wqb bf16 [256][128]
constexpr size_t F_H1    = F_SIM + 4194304;        // h1T bf16 (written after sim dead)
// w1b/w2b in PART6 dead sub-range (all other PART6 users stay below offset 540672).
constexpr size_t F_W1B   = F_PART6 + 1048576;      // 32768 floats (65536 u16)
constexpr size_t F_W2B   = F_PART6 + 1081344;      // 32768 floats

__device__ __forceinline__ u16 f2b(float x){      // fp32 -> bf16 RNE
  unsigned u = __float_as_uint(x);
  return (u16)((u + 0x7FFFu + ((u>>16)&1u)) >> 16);
}
__device__ __forceinline__ float b2f(u16 v){      // bf16 -> fp32
  return __uint_as_float((unsigned)v << 16);
}

// branch-free erf (Abramowitz-Stegun 7.1.26, max abs err 1.5e-7) + exact GELU
__device__ __forceinline__ float gelu_f(float v){
  float x = v*0.70710678f;
  float ax = fabsf(x);
  float t = __frcp_rn(1.0f + 0.3275911f*ax);   // v_rcp-based
  float p = 1.061405429f;
  p = p*t - 1.453152027f;
  p = p*t + 1.421413741f;
  p = p*t - 0.284496736f;
  p = p*t + 0.254829592f;
  p = p*t;
  float e = __expf(-ax*ax);
  float y = 1.0f - p*e;                        // erf(|x|)
  float er = copysignf(y, x);
  return 0.5f*v*(1.0f + er);
}

// ---- compile-time 33->64 upsample tables ----
struct UpT { int j0[64]; float fj[64]; };
constexpr UpT mkUp(){
  UpT t{};
  for (int o=0;o<64;++o){
    float x = ((float)o + 0.5f)*0.515625f - 0.5f;
    if (x < 0.f) x = 0.f;
    if (x > 32.f) x = 32.f;
    int j = (int)x; if (j > 31) j = 31;
    t.j0[o] = j; t.fj[o] = x - (float)j;
  }
  return t;
}
constexpr UpT UT = mkUp();

__device__ __forceinline__ void upfac(int o, int& j0, float& f){
  float x = ((float)o + 0.5f)*0.515625f - 0.5f;
  x = fminf(fmaxf(x, 0.f), 32.f);
  int j = (int)x; j = j < 31 ? j : 31;
  j0 = j; f = x - (float)j;
}

__device__ __forceinline__ void fma8(float (&a)[8], float qv, const float4& q0, const float4& q1){
  a[0] += qv*q0.x; a[1] += qv*q0.y; a[2] += qv*q0.z; a[3] += qv*q0.w;
  a[4] += qv*q1.x; a[5] += qv*q1.y; a[6] += qv*q1.z; a[7] += qv*q1.w;
}
__device__ __forceinline__ void fma8h(float (&a)[8], float qv, uint4 u){
  a[0] += qv*b2f((u16)(u.x&0xFFFFu)); a[1] += qv*b2f((u16)(u.x>>16));
  a[2] += qv*b2f((u16)(u.y&0xFFFFu)); a[3] += qv*b2f((u16)(u.y>>16));
  a[4] += qv*b2f((u16)(u.z&0xFFFFu)); a[5] += qv*b2f((u16)(u.z>>16));
  a[6] += qv*b2f((u16)(u.w&0xFFFFu)); a[7] += qv*b2f((u16)(u.w>>16));
}

// ---------------- k_pre: tables + 3x weight cvt + x transpose (5 launches -> 1) ----------------
__global__ __launch_bounds__(256) void k_pre(const float* __restrict__ x, const float* __restrict__ qkvw,
                                             const float* __restrict__ w1, const float* __restrict__ w2,
                                             float* __restrict__ W127, float* __restrict__ W64,
                                             u16* __restrict__ wqb, u16* __restrict__ w1b,
                                             u16* __restrict__ w2b, u16* __restrict__ xq){
  int blk = blockIdx.x, tid = threadIdx.x;
  if (blk == 0){
    int i = tid;
    if (i < 33){
      const float inv = 127.0f/33.0f;
      float xx = ((float)i + 0.5f)*inv - 0.5f;
      float s = 0.f;
      for (int j=0;j<127;++j){ float w = 1.0f - fabsf((float)j - xx)/inv; w = fmaxf(w,0.f); W127[i*127+j]=w; s+=w; }
      float r = 1.0f/s;
      for (int j=0;j<127;++j) W127[i*127+j] *= r;
    } else if (i < 66){
      int ii = i-33;
      const float inv = 64.0f/33.0f;
      float xx = ((float)ii + 0.5f)*inv - 0.5f;
      float s=0.f;
      for (int j=0;j<64;++j){ float w = 1.0f - fabsf((float)j - xx)/inv; w=fmaxf(w,0.f); W64[ii*64+j]=w; s+=w; }
      float r=1.0f/s;
      for (int j=0;j<64;++j) W64[ii*64+j]*=r;
    }
  } else if (blk < 129){
    int id = (blk-1)*256 + tid;
    if (id < 32768) wqb[id] = f2b(qkvw[id]);
  } else if (blk < 385){
    int id = (blk-129)*256 + tid;
    if (id < 65536) w1b[id] = f2b(w1[id]);
  } else if (blk < 641){
    int id = (blk-385)*256 + tid;
    if (id < 65536) w2b[id] = f2b(w2[id]);
  } else {
    __shared__ float T[128][66];
    int bx = blk - 641;
    int n = bx>>6, h = bx&63;
    for (int e=tid;e<8192;e+=256){
      int c = e>>6, w = e&63;                  // 64-float contiguous reads per c
      T[c][w] = x[(((size_t)(n*128+c))*64 + h)*64 + w];
    }
    __syncthreads();
    for (int e=tid;e<8192;e+=256){
      int w = e>>7, c = e&127;                 // 256B contiguous u16 stores per w
      xq[(((size_t)(n*64+w))*64 + h)*128 + c] = f2b(T[c][w]);
    }
  }
}

// ---------------- k_qkvp1: QKV MFMA GEMM (blk<512) + pos1 (blk 512..1035) ----------------
__global__ __launch_bounds__(256) void k_qkvp1(const u16* __restrict__ xq, const u16* __restrict__ wqb,
                                               u16* __restrict__ qkvT, float2* __restrict__ part,
                                               const float* __restrict__ base, const float* __restrict__ W127,
                                               float* __restrict__ tmp){
  if (blockIdx.x < 512){
    int b = blockIdx.x;
    int tid = threadIdx.x;
    int wv = tid>>6, l = tid&63;
    int wn = wv*64;
    int lr = l&15, lq = l>>4;
    __shared__ u16 As[64*40];
    __shared__ u16 Bs[256*40];
    f32x4 acc[4][4];
    #pragma unroll
    for (int mi=0;mi<4;++mi)
      #pragma unroll
      for (int ni=0;ni<4;++ni) acc[mi][ni] = (f32x4){0.f,0.f,0.f,0.f};
    const u16* Ag = xq + (size_t)b*8192;      // [64][128]
    const u16* Bg = wqb;                       // [256][128]
    for (int ks=0; ks<128; ks+=32){
      __syncthreads();
      { int e = tid; int row = e>>2, q = e&3;
        *(uint4*)&As[row*40 + q*8] = *(const uint4*)&Ag[(size_t)row*128 + ks + q*8]; }
      #pragma unroll
      for (int p=0;p<4;++p){
        int e = tid + p*256; int row = e>>2, q = e&3;
        *(uint4*)&Bs[row*40 + q*8] = *(const uint4*)&Bg[(size_t)row*128 + ks + q*8];
      }
      __syncthreads();
      bf16x8 af[4], bfr[4];
      #pragma unroll
      for (int mi=0;mi<4;++mi) af[mi] = *(const bf16x8*)&As[(mi*16 + lr)*40 + lq*8];
      #pragma unroll
      for (int ni=0;ni<4;++ni) bfr[ni] = *(const bf16x8*)&Bs[(wn + ni*16 + lr)*40 + lq*8];
      #pragma unroll
      for (int mi=0;mi<4;++mi)
        #pragma unroll
        for (int ni=0;ni<4;++ni)
          acc[mi][ni] = __builtin_amdgcn_mfma_f32_16x16x32_bf16(af[mi], bfr[ni], acc[mi][ni], 0,0,0);
    }
    // epilogue: bf16 C store + per-channel (o) fp32 partial sums over l (this b)
    float cs[4] = {0.f,0.f,0.f,0.f}, cq[4] = {0.f,0.f,0.f,0.f};
    u16* ob = qkvT + (size_t)b*16384;
    #pragma unroll
    for (int mi=0;mi<4;++mi)
      #pragma unroll
      for (int r=0;r<4;++r){
        int row = mi*16 + lq*4 + r;
        #pragma unroll
        for (int ni=0;ni<4;++ni){
          float v = acc[mi][ni][r];
          ob[(size_t)row*256 + wn + ni*16 + lr] = f2b(v);
          cs[ni] += v; cq[ni] += v*v;
        }
      }
    #pragma unroll
    for (int ni=0;ni<4;++ni){
      cs[ni] += __shfl_xor(cs[ni], 16); cs[ni] += __shfl_xor(cs[ni], 32);
      cq[ni] += __shfl_xor(cq[ni], 16); cq[ni] += __shfl_xor(cq[ni], 32);
    }
    if (lq == 0){
      #pragma unroll
      for (int ni=0;ni<4;++ni)
        part[(size_t)(wn + ni*16 + lr)*512 + b] = make_float2(cs[ni], cq[ni]);
    }
  } else {
    int id = (blockIdx.x-512)*256 + threadIdx.x;
    if (id >= 32*33*127) return;
    int c = id / 4191; int r = id - c*4191; int i = r / 127; int xx = r - i*127;
    const float* wr = W127 + i*127;
    const float* bc = base + c*16129 + xx;
    float a=0.f;
    for (int y=0;y<127;++y) a += wr[y]*bc[y*127];
    tmp[id] = a;
  }
}

// ---------------- k_st2p2: qkv BN stats (blk<8) + pos2 (blk 8..144) ----------------
__global__ __launch_bounds__(256) void k_st2p2(const float2* __restrict__ part, const float* __restrict__ g,
                                               const float* __restrict__ bta, float2* __restrict__ st,
                                               const float* __restrict__ tmp, const float* __restrict__ W127,
                                               float* __restrict__ pos){
  if (blockIdx.x < 8){
    int t = threadIdx.x;
    int chL = t>>3, seg = t&7;
    int ch = blockIdx.x*32 + chL;
    float s=0.f, s2=0.f;
    const float2* p = part + (size_t)ch*512 + seg*64;
    #pragma unroll 8
    for (int r=0;r<64;++r){ float2 q = p[r]; s+=q.x; s2+=q.y; }
    __shared__ float A[32][9], Bq[32][9];
    A[chL][seg]=s; Bq[chL][seg]=s2; __syncthreads();
    if (seg==0){
      #pragma unroll
      for (int k=1;k<8;++k){ s += A[chL][k]; s2 += Bq[chL][k]; }
      float m = s*(1.0f/32768.0f);
      float var = s2*(1.0f/32768.0f) - m*m;
      float sc = g[ch]/sqrtf(var + EPSV);
      st[ch] = make_float2(sc, bta[ch] - m*sc);
    }
  } else {
    int id = (blockIdx.x-8)*256 + threadIdx.x;
    if (id >= 32*33*33) return;
    int c = id / 1089; int r = id - c*1089; int i = r / 33; int j = r - i*33;
    const float* wr = W127 + j*127;
    const float* tc = tmp + c*4191 + i*127;
    float a=0.f;
    for (int xx=0;xx<127;++xx) a += wr[xx]*tc[xx];
    pos[id] = a;
  }
}

// ---------------- k_qkvr_kv: qkvr (blk<512) + keT (512..546) + veP (547..678) ----------------
__global__ __launch_bounds__(256) void k_qkvr_kv(const u16* __restrict__ qkvT, const float* __restrict__ W64,
                                                 const float2* __restrict__ st, u16* __restrict__ qkvrT,
                                                 const float* __restrict__ pos, float* __restrict__ keT,
                                                 u16* __restrict__ VeP){
  int blk = blockIdx.x;
  if (blk < 512){
    int b = blk, ch = threadIdx.x;
    const u16* base = qkvT + (size_t)b*16384 + ch;
    float xr[64];
    #pragma unroll
    for (int t=0;t<64;++t) xr[t] = b2f(base[t*256]);
    float2 sb = st[ch];
    u16* ob = qkvrT + (size_t)b*8448 + ch;
    for (int i=0;i<33;++i){
      const float4* wr = (const float4*)(W64 + i*64);
      float a = 0.f;
      #pragma unroll
      for (int q=0;q<16;++q){
        float4 w4 = wr[q];
        a += w4.x*xr[4*q] + w4.y*xr[4*q+1] + w4.z*xr[4*q+2] + w4.w*xr[4*q+3];
      }
      ob[i*256] = f2b(a*sb.x + sb.y);
    }
  } else if (blk < 547){
    int id = (blk-512)*256 + threadIdx.x;
    if (id >= 8712) return;
    int c = id / 1089; int r = id - c*1089; int i = r / 33; int j = r - i*33;
    keT[id] = pos[(8+c)*1089 + j*33 + i];
  } else {
    int id = (blk-547)*256 + threadIdx.x;
    if (id >= 33792) return;
    int c = id & 15;
    int i = (id >> 4) & 63;
    int k = id >> 10;
    int i0; float fi; upfac(i, i0, fi);
    const float* P = pos + (16+c)*1089;
    VeP[id] = f2b((1.f-fi)*P[i0*33 + k] + fi*P[(i0+1)*33 + k]);
  }
}

// ---------------- sim = concat([qk, qr, kr]) bf16 + per-block stats partials (fp32) ----------------
__global__ __launch_bounds__(256) void k_sim(const u16* __restrict__ qkvrT, const float* __restrict__ pos,
                                             const float* __restrict__ keT,
                                             u16* __restrict__ sim, float* __restrict__ part6){
  int b = blockIdx.x, g = blockIdx.y;
  __shared__ float lqa[264], lka[264];
  int tid = threadIdx.x;
  for (int e=tid;e<528;e+=256){
    int half = (e < 264) ? 0 : 1;
    int e2 = e - half*264;
    int c = e2/33, i = e2 - c*33;
    float v = b2f(qkvrT[(size_t)b*8448 + i*256 + (g*32 + half*8 + c)]);
    if (half==0) lqa[e2]=v; else lka[e2]=v;
  }
  __syncthreads();
  float sqk=0.f,qqk=0.f,sqr=0.f,qqr=0.f,skr=0.f,qkr=0.f;
  for (int p=tid;p<1089;p+=256){
    int i = p/33, j = p - i*33;
    float qk=0.f, qr=0.f, kr=0.f;
    #pragma unroll
    for (int c=0;c<8;++c){
      float qa_ = lqa[c*33+i];
      float ka_ = lka[c*33+j];
      qk += qa_*ka_;
      qr += qa_*pos[c*1089 + i*33 + j];
      kr += ka_*keT[c*1089 + i*33 + j];
    }
    sim[(size_t)(b*24 + g)*1089 + p] = f2b(qk);
    sim[(size_t)(b*24 + 8 + g)*1089 + p] = f2b(qr);
    sim[(size_t)(b*24 + 16 + g)*1089 + p] = f2b(kr);
    sqk+=qk; qqk+=qk*qk; sqr+=qr; qqr+=qr*qr; skr+=kr; qkr+=kr*kr;
  }
  __shared__ float red[6][256];
  red[0][tid]=sqk; red[1][tid]=qqk; red[2][tid]=sqr;
  red[3][tid]=qqr; red[4][tid]=skr; red[5][tid]=qkr;
  __syncthreads();
  for (int o=128;o>0;o>>=1){
    if (tid<o){
      #pragma unroll
      for (int c=0;c<6;++c) red[c][tid]+=red[c][tid+o];
    }
    __syncthreads();
  }
  if (tid<6) part6[(size_t)(b*8+g)*6 + tid] = red[tid][0];
}

// ---------------- simst from part6 ----------------
__global__ void k_sstB(const float* __restrict__ part6, const float* __restrict__ g,
                       const float* __restrict__ bta, float2* __restrict__ st){
  int nb = threadIdx.x;
  if (nb >= 192) return;
  int n = nb/24, ch = nb - n*24;
  int t3 = ch>>3, gg = ch&7;
  float s=0.f, s2=0.f;
  for (int w=0; w<64; ++w){
    const float* p = part6 + (size_t)((n*64+w)*8 + gg)*6 + 2*t3;
    s += p[0]; s2 += p[1];
  }
  float m = s*(1.0f/69696.0f);
  float var = s2*(1.0f/69696.0f) - m*m;
  float sc = g[ch]/sqrtf(var + EPSV);
  st[nb] = make_float2(sc, bta[ch] - m*sc);
}

// ---------------- fused attention (r23-measured): channel-half split, chunk-of-11 phase B ----------------
__global__ __launch_bounds__(256,4) void k_attn(const u16* __restrict__ sim, const float2* __restrict__ simst,
                                                const u16* __restrict__ qkvrT, const u16* __restrict__ veP,
                                                u16* __restrict__ so){
  int tid = threadIdx.x;
  int wv = tid >> 6;
  int i  = tid & 63;
  int pr   = wv >> 1;      // bg slot within block
  int half = wv & 1;       // channel half: 0 -> c 0..7, 1 -> c 8..15
  __shared__ float  S[2][1092];
  __shared__ float4 Va[2][132];
  // cooperative staging of 2 bg tiles
  #pragma unroll
  for (int p2=0;p2<2;++p2){
    int bg2 = blockIdx.x*2 + p2;
    int b2 = bg2>>3, g2 = bg2&7, n2 = b2>>6;
    float2 sb0 = simst[n2*24 + g2], sb1 = simst[n2*24 + 8 + g2], sb2 = simst[n2*24 + 16 + g2];
    float badd = sb0.y + sb1.y + sb2.y;
    const u16* s0 = sim + ((size_t)b2*24 + g2)*1089;
    for (int e=tid;e<1089;e+=256)
      S[p2][e] = b2f(s0[e])*sb0.x + b2f(s0[e+8712])*sb1.x + b2f(s0[e+17424])*sb2.x + badd;
    for (int e=tid;e<132;e+=256){
      int j = e>>2, cq = e&3;
      const u16* qp = qkvrT + (size_t)b2*8448 + j*256 + g2*32 + 16 + cq*4;
      uint2 u = *(const uint2*)qp;
      Va[p2][e] = make_float4(b2f((u16)(u.x&0xFFFFu)), b2f((u16)(u.x>>16)),
                              b2f((u16)(u.y&0xFFFFu)), b2f((u16)(u.y>>16)));
    }
  }
  __syncthreads();

  int bg = blockIdx.x*2 + pr;
  int b = bg>>3, g = bg&7;

  // phase A: i-lerped score row, exp, fold into qk[33] (duplicated across the wave pair)
  int i0; float fi; upfac(i, i0, fi);
  const float* R0 = S[pr] + i0*33;
  float rowv[33];
  #pragma unroll
  for (int k=0;k<33;++k) rowv[k] = R0[k] + fi*(R0[k+33] - R0[k]);
  float qk[33];
  #pragma unroll
  for (int k=0;k<33;++k) qk[k] = 0.f;
  float s = 0.f;
  #pragma unroll
  for (int j=0;j<64;++j){
    float fj = UT.fj[j]; int j0 = UT.j0[j];
    float v = rowv[j0] + fj*(rowv[j0+1] - rowv[j0]);
    float e = __expf(v);
    s += e;
    qk[j0]   += e*(1.f-fj);
    qk[j0+1] += e*fj;
  }
  float inv = 1.f/s;

  // phase B: this wave's 8-channel half; chunk-of-11 loads (compiler schedules ~3 in flight)
  float av[8], ae[8];
  #pragma unroll
  for (int c=0;c<8;++c){ av[c]=0.f; ae[c]=0.f; }
  const uint4* vp  = (const uint4*)veP + (size_t)i*2 + half;   // one uint4 (8 ch) per k
  const float4* va4 = &Va[pr][half*2];                          // two float4 (8 ch) per k
  #pragma unroll
  for (int kc=0; kc<33; kc+=11){
    uint4 e0 = vp[(kc+0)*128],  e1 = vp[(kc+1)*128],  e2 = vp[(kc+2)*128];
    uint4 e3 = vp[(kc+3)*128],  e4 = vp[(kc+4)*128],  e5 = vp[(kc+5)*128];
    uint4 e6 = vp[(kc+6)*128],  e7 = vp[(kc+7)*128],  e8 = vp[(kc+8)*128];
    uint4 e9 = vp[(kc+9)*128],  e10= vp[(kc+10)*128];
    // LDS-fed work covers global latency
    #pragma unroll
    for (int t2=0;t2<11;++t2)
      fma8(av, qk[kc+t2], va4[(kc+t2)*4+0], va4[(kc+t2)*4+1]);
    // consume globals (unpack bf16)
    fma8h(ae, qk[kc+0], e0);  fma8h(ae, qk[kc+1], e1);  fma8h(ae, qk[kc+2], e2);
    fma8h(ae, qk[kc+3], e3);  fma8h(ae, qk[kc+4], e4);  fma8h(ae, qk[kc+5], e5);
    fma8h(ae, qk[kc+6], e6);  fma8h(ae, qk[kc+7], e7);  fma8h(ae, qk[kc+8], e8);
    fma8h(ae, qk[kc+9], e9);  fma8h(ae, qk[kc+10], e10);
  }
  u16* ob = so + (size_t)b*16384 + g*2048 + (half*8)*128;
  #pragma unroll
  for (int c=0;c<8;++c){
    ob[c*128 + i]      = f2b(av[c]*inv);
    ob[c*128 + 64 + i] = f2b(ae[c]*inv);
  }
}

// ---------------- so BN stats, 2-stage (bf16 so) ----------------
__global__ __launch_bounds__(256) void k_sost1(const u16* __restrict__ so, float2* __restrict__ part){
  int ch = blockIdx.x, rowG = blockIdx.y;   // 256 x 8
  int tid = threadIdx.x;
  int rs = tid>>6, l = tid&63;
  float s=0.f, s2=0.f;
  for (int r = rowG*64 + rs; r < rowG*64 + 64; r += 4){
    float v = b2f(so[((size_t)r*256 + ch)*64 + l]); s+=v; s2+=v*v;
  }
  __shared__ float S1[256], S2[256];
  S1[tid]=s; S2[tid]=s2; __syncthreads();
  for (int o=128;o>0;o>>=1){ if(tid<o){ S1[tid]+=S1[tid+o]; S2[tid]+=S2[tid+o]; } __syncthreads(); }
  if (tid==0) part[ch*8 + rowG] = make_float2(S1[0], S2[0]);
}
__global__ void k_sost2(const float2* __restrict__ part, const float* __restrict__ g,
                        const float* __restrict__ bta, float2* __restrict__ st){
  int ch = threadIdx.x;   // 256
  float s=0.f, s2=0.f;
  #pragma unroll
  for (int r=0;r<8;++r){ float2 p = part[ch*8 + r]; s+=p.x; s2+=p.y; }
  float m = s*(1.0f/32768.0f);
  float var = s2*(1.0f/32768.0f) - m*m;
  float sc = g[ch]/sqrtf(var + EPSV);
  st[ch] = make_float2(sc, bta[ch] - m*sc);
}

// ---------------- BN(so) + pair-sum + transpose -> o + xo-stats partials ----------------
__global__ __launch_bounds__(256) void k_o(const u16* __restrict__ so, const float2* __restrict__ st,
                                           float* __restrict__ o, float* __restrict__ opart){
  __shared__ float T[64][65];
  __shared__ float R1[256], R2[256];
  int n = blockIdx.x>>7, oc = blockIdx.x&127;
  int tid = threadIdx.x;
  float2 s0 = st[2*oc], s1 = st[2*oc+1];
  float badd = s0.y + s1.y;
  for (int e=tid;e<4096;e+=256){
    int w = e>>6, h = e&63;                  // lanes along h: contiguous so reads
    const u16* sb = so + (size_t)(n*64+w)*16384 + (2*oc)*64;
    T[w][h] = b2f(sb[h])*s0.x + b2f(sb[64+h])*s1.x + badd;
  }
  __syncthreads();
  for (int e=tid;e<4096;e+=256){
    int h = e>>6, w = e&63;                  // lanes along w: contiguous o writes
    o[(((size_t)(n*128+oc))*64 + h)*64 + w] = T[w][h];
  }
  // ---- stats partials (T intact) ----
  float fs=0.f, fq=0.f;
  for (int e=tid;e<4096;e+=256){ float v = T[e>>6][e&63]; fs+=v; fq+=v*v; }
  R1[tid]=fs; R2[tid]=fq; __syncthreads();
  for (int o2=128;o2>0;o2>>=1){ if(tid<o2){ R1[tid]+=R1[tid+o2]; R2[tid]+=R2[tid+o2]; } __syncthreads(); }
  float* rec = opart + (size_t)(n*128+oc)*18;
  if (tid==0){ rec[0]=R1[0]; rec[1]=R2[0]; }
  if (tid < 64){
    int l = tid;                             // wave 0, lane l = h index
    float c0=T[0][l], c1=T[1][l], c62=T[62][l], c63=T[63][l];
    float d0=c0*c0, d1=c1*c1, d62=c62*c62, d63=c63*c63;
    #pragma unroll
    for (int off=32; off; off>>=1){
      c0+=__shfl_xor(c0,off); c1+=__shfl_xor(c1,off);
      c62+=__shfl_xor(c62,off); c63+=__shfl_xor(c63,off);
      d0+=__shfl_xor(d0,off); d1+=__shfl_xor(d1,off);
      d62+=__shfl_xor(d62,off); d63+=__shfl_xor(d63,off);
    }
    if (l==0){
      rec[2]=c0; rec[3]=d0; rec[4]=c1; rec[5]=d1;
      rec[6]=c62; rec[7]=d62; rec[8]=c63; rec[9]=d63;
    }
  } else if (tid < 128){
    int l = tid & 63;                        // wave 1, lane l = w index
    float r0=T[l][0], r1=T[l][1], r62=T[l][62], r63=T[l][63];
    float e0=r0*r0, e1=r1*r1, e62=r62*r62, e63=r63*r63;
    #pragma unroll
    for (int off=32; off; off>>=1){
      r0+=__shfl_xor(r0,off); r1+=__shfl_xor(r1,off);
      r62+=__shfl_xor(r62,off); r63+=__shfl_xor(r63,off);
      e0+=__shfl_xor(e0,off); e1+=__shfl_xor(e1,off);
      e62+=__shfl_xor(e62,off); e63+=__shfl_xor(e63,off);
    }
    if (l==0){
      rec[10]=r0; rec[11]=e0; rec[12]=r1; rec[13]=e1;
      rec[14]=r62; rec[15]=e62; rec[16]=r63; rec[17]=e63;
    }
  }
}

// ---------------- xo instance-norm stats from k_o plane records ----------------
__global__ void k_instB(const float* __restrict__ opart, const float* __restrict__ g,
                        const float* __restrict__ bta, float2* __restrict__ st){
  int nb = blockIdx.x*256 + threadIdx.x;
  if (nb >= 1024) return;
  int n = nb>>7, c = nb&127;
  float s, q;
  if (c >= 40){
    const float* r = opart + (size_t)(n*128+c)*18;
    s = r[0]; q = r[1];
  } else {
    int grp = c/10, cc = c - grp*10;
    const float* r = opart + (size_t)(n*128+cc)*18;
    if (grp==0){ s = r[0]-r[6]-r[8];   q = r[1]-r[7]-r[9];  }
    else if (grp==1){ s = r[0]-r[2]-r[4];   q = r[1]-r[3]-r[5];  }
    else if (grp==2){ s = r[0]-r[14]-r[16]; q = r[1]-r[15]-r[17];}
    else            { s = r[0]-r[10]-r[12]; q = r[1]-r[11]-r[13];}
  }
  float m = s*(1.0f/4096.0f);
  float var = q*(1.0f/4096.0f) - m*m;
  float sc = g[c]/sqrtf(var + EPSV);
  st[nb] = make_float2(sc, bta[c] - m*sc);
}

// ---------------- spatial block ----------------
__device__ __forceinline__ float xo_val(const float* __restrict__ o, int n, int c, int h, int w){
  if (c >= 40) return o[((n*128 + c)*64 + h)*64 + w];
  int grp = c / 10;
  int cc = c - grp*10;
  int base = (n*128 + cc)*64;
  if (grp==0) return (w>=2) ? o[(base + h)*64 + (w-2)] : 0.f;
  if (grp==1) return (w<62) ? o[(base + h)*64 + (w+2)] : 0.f;
  if (grp==2) return (h>=2) ? o[(base + (h-2))*64 + w] : 0.f;
  return (h<62) ? o[(base + (h+2))*64 + w] : 0.f;
}

// ---------------- fused: instance-norm(xo) + transpose -> xnT bf16 [n][hw][c] ----------------
__global__ __launch_bounds__(256) void k_xnt(const float* __restrict__ o, const float2* __restrict__ st,
                                             u16* __restrict__ xnT){
  __shared__ float T[64][65];
  int h = blockIdx.x&63, c0 = ((blockIdx.x>>6)&1)*64, n = blockIdx.x>>7;
  int tid = threadIdx.x;
  for (int e=tid;e<4096;e+=256){
    int cL = e>>6, w = e&63;                 // lanes along w: coalesced xo_val reads
    float2 sb = st[n*128 + c0+cL];           // wave-uniform
    T[cL][w] = xo_val(o, n, c0+cL, h, w)*sb.x + sb.y;
  }
  __syncthreads();
  for (int e=tid;e<4096;e+=256){
    int wL = e>>6, cL = e&63;                // lanes along c: 128B contiguous stores
    xnT[((size_t)(n*4096 + h*64 + wL))*128 + c0 + cL] = f2b(T[cL][wL]);
  }
}

// ---------------- mlp1: D[128 hw][64 co] per block, 4 waves (2x2 of 64x32); grid (32,8,8)=2048 ----
__global__ __launch_bounds__(256) void k_mlp1(const u16* __restrict__ xnT, const u16* __restrict__ w1b,
                                              u16* __restrict__ h1T){
  int hw0 = blockIdx.x*128, co0 = blockIdx.y*64, n = blockIdx.z;
  int tid = threadIdx.x;
  int wv = tid>>6, l = tid&63;
  int wm = (wv>>1)*64, wn = (wv&1)*32;
  int lr = l&15, lq = l>>4;
  __shared__ u16 As[128*40];
  __shared__ u16 Bs[64*40];
  f32x4 acc[4][2];
  #pragma unroll
  for (int mi=0;mi<4;++mi)
    #pragma unroll
    for (int ni=0;ni<2;++ni) acc[mi][ni] = (f32x4){0.f,0.f,0.f,0.f};
  const u16* Ag = xnT + ((size_t)(n*4096 + hw0))*128;
  const u16* Bg = w1b + (size_t)co0*128;
  for (int ks=0; ks<128; ks+=32){
    __syncthreads();
    #pragma unroll
    for (int p=0;p<2;++p){
      int e = tid + p*256; int row = e>>2, q = e&3;
      *(uint4*)&As[row*40 + q*8] = *(const uint4*)&Ag[(size_t)row*128 + ks + q*8];
    }
    { int e = tid; int row = e>>2, q = e&3;
      *(uint4*)&Bs[row*40 + q*8] = *(const uint4*)&Bg[(size_t)row*128 + ks + q*8]; }
    __syncthreads();
    bf16x8 af[4], bfr[2];
    #pragma unroll
    for (int mi=0;mi<4;++mi) af[mi] = *(const bf16x8*)&As[(wm + mi*16 + lr)*40 + lq*8];
    #pragma unroll
    for (int ni=0;ni<2;++ni) bfr[ni] = *(const bf16x8*)&Bs[(wn + ni*16 + lr)*40 + lq*8];
    #pragma unroll
    for (int mi=0;mi<4;++mi)
      #pragma unroll
      for (int ni=0;ni<2;++ni)
        acc[mi][ni] = __builtin_amdgcn_mfma_f32_16x16x32_bf16(af[mi], bfr[ni], acc[mi][ni], 0,0,0);
  }
  u16* ob = h1T + ((size_t)(n*4096 + hw0 + wm))*512 + co0 + wn;
  #pragma unroll
  for (int mi=0;mi<4;++mi)
    #pragma unroll
    for (int r=0;r<4;++r){
      int row = mi*16 + lq*4 + r;
      #pragma unroll
      for (int ni=0;ni<2;++ni){
        float v = acc[mi][ni][r];
        ob[(size_t)row*512 + ni*16 + lr] = f2b(gelu_f(v));
      }
    }
}

// ---------------- mlp2: split-K(2) + hw-tile 64; grid (64,2,8)=1024, atomicAdd commit ----
__global__ __launch_bounds__(256) void k_mlp2(const u16* __restrict__ w2b, const u16* __restrict__ h1T,
                                              float* __restrict__ out){
  int hw0 = blockIdx.x*64, n = blockIdx.z;
  int ks0 = blockIdx.y*256;                 // K half: [ks0, ks0+256)
  int tid = threadIdx.x;
  int wv = tid>>6, l = tid&63;
  int wm = (wv>>1)*64, wn = (wv&1)*32;      // wm: co offset, wn: hw offset
  int lr = l&15, lq = l>>4;
  __shared__ u16 As[128*40];
  __shared__ u16 Bs[64*40];
  f32x4 acc[4][2];
  #pragma unroll
  for (int mi=0;mi<4;++mi)
    #pragma unroll
    for (int ni=0;ni<2;++ni) acc[mi][ni] = (f32x4){0.f,0.f,0.f,0.f};
  const u16* Ag = w2b;
  const u16* Bg = h1T + ((size_t)(n*4096 + hw0))*512;
  for (int ks=ks0; ks<ks0+256; ks+=32){
    __syncthreads();
    #pragma unroll
    for (int p=0;p<2;++p){
      int e = tid + p*256; int row = e>>2, q = e&3;
      *(uint4*)&As[row*40 + q*8] = *(const uint4*)&Ag[(size_t)row*512 + ks + q*8];
    }
    { int e = tid; int row = e>>2, q = e&3;
      *(uint4*)&Bs[row*40 + q*8] = *(const uint4*)&Bg[(size_t)row*512 + ks + q*8]; }
    __syncthreads();
    bf16x8 af[4], bfr[2];
    #pragma unroll
    for (int mi=0;mi<4;++mi) af[mi] = *(const bf16x8*)&As[(wm + mi*16 + lr)*40 + lq*8];
    #pragma unroll
    for (int ni=0;ni<2;++ni) bfr[ni] = *(const bf16x8*)&Bs[(wn + ni*16 + lr)*40 + lq*8];
    #pragma unroll
    for (int mi=0;mi<4;++mi)
      #pragma unroll
      for (int ni=0;ni<2;++ni)
        acc[mi][ni] = __builtin_amdgcn_mfma_f32_16x16x32_bf16(af[mi], bfr[ni], acc[mi][ni], 0,0,0);
  }
  #pragma unroll
  for (int mi=0;mi<4;++mi)
    #pragma unroll
    for (int r=0;r<4;++r){
      int cout = wm + mi*16 + lq*4 + r;
      #pragma unroll
      for (int ni=0;ni<2;++ni){
        size_t idx = ((size_t)(n*128 + cout))*4096 + hw0 + wn + ni*16 + lr;
        atomicAdd(&out[idx], acc[mi][ni][r]);
      }
    }
}

extern "C" void kernel_launch(void* const* d_in, const int* in_sizes, int n_in,
                              void* d_out, int out_size, void* d_ws, size_t ws_size,
                              hipStream_t stream) {
  (void)in_sizes; (void)n_in; (void)out_size; (void)ws_size;
  const float* x       = (const float*)d_in[0];
  const float* qkvw    = (const float*)d_in[1];
  const float* bng     = (const float*)d_in[2];
  const float* bnb     = (const float*)d_in[3];
  const float* baserel = (const float*)d_in[4];
  const float* simg    = (const float*)d_in[5];
  const float* simb    = (const float*)d_in[6];
  const float* outg    = (const float*)d_in[7];
  const float* outb    = (const float*)d_in[8];
  const float* ing     = (const float*)d_in[9];
  const float* inb     = (const float*)d_in[10];
  const float* w1      = (const float*)d_in[11];
  const float* w2      = (const float*)d_in[12];

  float* ws = (float*)d_ws;
  float*  W127  = ws + F_W127;
  float*  W64   = ws + F_W64;
  float2* qkvst = (float2*)(ws + F_QKVST);
  float2* simst = (float2*)(ws + F_SIMST);
  float2* sost  = (float2*)(ws + F_SOST);
  float2* inst  = (float2*)(ws + F_INST);
  float*  postmp= ws + F_POSTMP;
  float*  pos   = ws + F_POS;
  u16*    qkvT  = (u16*)(ws + F_QKV);
  u16*    qkvrT = (u16*)(ws + F_QKVR);
  u16*    sim   = (u16*)(ws + F_SIM);
  float*  part6 = ws + F_PART6;
  float2* sopart= (float2*)(ws + F_PART6);   // reuse after k_sstB (part6 dead)
  float2* bnp   = (float2*)(ws + F_BNP2);    // qkv BN partials (k_qkvp1..k_st2p2)
  float*  opart = ws + F_BNP2;               // plane stat records (k_o..k_instB); bnp dead by then
  u16*    wqb   = (u16*)(ws + F_WQB);        // bf16 qkv weight
  u16*    veP   = (u16*)(ws + F_VEH);
  u16*    xnT   = (u16*)(ws + F_XNT);
  float*  keT   = ws + F_KET;
  u16*    so    = (u16*)(ws + F_SO);
  u16*    xq    = (u16*)(ws + F_XQ);
  u16*    h1T   = (u16*)(ws + F_H1);
  u16*    w1b   = (u16*)(ws + F_W1B);        // in PART6 dead sub-range (>= +1048576)
  u16*    w2b   = (u16*)(ws + F_W2B);
  float*  out   = (float*)d_out;

  k_pre     <<<dim3(1153),     dim3(256), 0, stream>>>(x, qkvw, w1, w2, W127, W64, wqb, w1b, w2b, xq);
  k_qkvp1   <<<dim3(1036),     dim3(256), 0, stream>>>(xq, wqb, qkvT, bnp, baserel, W127, postmp);
  k_st2p2   <<<dim3(145),      dim3(256), 0, stream>>>(bnp, bng, bnb, qkvst, postmp, W127, pos);
  k_qkvr_kv <<<dim3(679),      dim3(256), 0, stream>>>(qkvT, W64, qkvst, qkvrT, pos, keT, veP);
  k_sim     <<<dim3(512,8),    dim3(256), 0, stream>>>(qkvrT, pos, keT, sim, part6);
  k_sstB    <<<dim3(1),        dim3(192), 0, stream>>>(part6, simg, simb, simst);
  k_attn    <<<dim3(2048),     dim3(256), 0, stream>>>(sim, simst, qkvrT, veP, so);
  k_sost1   <<<dim3(256,8),    dim3(256), 0, stream>>>(so, sopart);
  k_sost2   <<<dim3(1),        dim3(256), 0, stream>>>(sopart, outg, outb, sost);
  k_o       <<<dim3(1024),     dim3(256), 0, stream>>>(so, sost, out, opart);
  k_instB   <<<dim3(4),        dim3(256), 0, stream>>>(opart, ing, inb, inst);
  k_xnt     <<<dim3(1024),     dim3(256), 0, stream>>>(out, inst, xnT);
  k_mlp1    <<<dim3(32,8,8),   dim3(256), 0, stream>>>(xnT, w1b, h1T);
  k_mlp2    <<<dim3(64,2,8),   dim3(256), 0, stream>>>(w2b, h1T, out);
}

// Round 28
// 210.557 us; speedup vs baseline: 1.0454x; 1.0024x over previous
//
#include <hip/hip_runtime.h>
#include <math.h>

// Problem constants: N=8, C=128, H=64, W=64, B=N*W=512, ADJ=33, G=8, GP=16
constexpr float EPSV = 1e-5f;
typedef unsigned short u16;
using bf16x8 = __attribute__((ext_vector_type(8))) short;
using f32x4  = __attribute__((ext_vector_type(4))) float;

// ---------------- workspace layout (offsets in floats) ----------------
constexpr size_t F_W127  = 0;
constexpr size_t F_W64   = F_W127 + 4224;
constexpr size_t F_QKVST = F_W64  + 2112;
constexpr size_t F_SIMST = F_QKVST+ 512;
constexpr size_t F_SOST  = F_SIMST+ 384;
constexpr size_t F_INST  = F_SOST + 512;
constexpr size_t F_POSTMP= F_INST + 2048;          // 134112 (pos1 tmp; dead after pos2)
constexpr size_t F_POS   = F_POSTMP + 134112;      // 34848
constexpr size_t F_QKV   = F_POS  + 34848;         // qkvT u16 [512][64][256] (alias: SO u16 later)
constexpr size_t F_QKVR  = F_QKV  + 8388608;       // qkvrT u16 [512][33][256]
constexpr size_t F_SIM   = F_QKVR + 4325376;       // sim u16 13381632 elems (alias: XQ early, h1T later)
constexpr size_t F_PART6 = F_SIM  + 13381632;      // region: part6 / sopart / bnp / opart / wqb / w1b / w2b
constexpr size_t F_VEH   = F_PART6 + 4460544;      // VeP u16 33792 elems
constexpr size_t F_XNT   = F_VEH  + 33792;         // xnT bf16 = 2097152 f
constexpr size_t F_KET   = F_XNT  + 2097152;       // keT 8712
constexpr size_t F_SO    = F_QKV;                  // so u16 [512][256][64] (after qkvT dead)
constexpr size_t F_XQ    = F_SIM;                  // xq bf16 [512][64][128] (dies before k_sim)
constexpr size_t F_BNP2  = F_PART6 + 262144;       // qkv BN partials; then opart (k_o..k_instB)
constexpr size_t F_WQB   = F_PART6 + 524288;       // wqb bf16 [256][128]
constexpr size_t F_H1    = F_SIM + 4194304;        // h1T bf16 (written after sim dead)
// w1b/w2b in PART6 dead sub-range (all other PART6 users stay below offset 540672).
constexpr size_t F_W1B   = F_PART6 + 1048576;      // 32768 floats (65536 u16)
constexpr size_t F_W2B   = F_PART6 + 1081344;      // 32768 floats

__device__ __forceinline__ u16 f2b(float x){      // fp32 -> bf16 RNE
  unsigned u = __float_as_uint(x);
  return (u16)((u + 0x7FFFu + ((u>>16)&1u)) >> 16);
}
__device__ __forceinline__ float b2f(u16 v){      // bf16 -> fp32
  return __uint_as_float((unsigned)v << 16);
}

// branch-free erf (Abramowitz-Stegun 7.1.26, max abs err 1.5e-7) + exact GELU
__device__ __forceinline__ float gelu_f(float v){
  float x = v*0.70710678f;
  float ax = fabsf(x);
  float t = __frcp_rn(1.0f + 0.3275911f*ax);   // v_rcp-based
  float p = 1.061405429f;
  p = p*t - 1.453152027f;
  p = p*t + 1.421413741f;
  p = p*t - 0.284496736f;
  p = p*t + 0.254829592f;
  p = p*t;
  float e = __expf(-ax*ax);
  float y = 1.0f - p*e;                        // erf(|x|)
  float er = copysignf(y, x);
  return 0.5f*v*(1.0f + er);
}

// ---- compile-time 33->64 upsample tables ----
struct UpT { int j0[64]; float fj[64]; };
constexpr UpT mkUp(){
  UpT t{};
  for (int o=0;o<64;++o){
    float x = ((float)o + 0.5f)*0.515625f - 0.5f;
    if (x < 0.f) x = 0.f;
    if (x > 32.f) x = 32.f;
    int j = (int)x; if (j > 31) j = 31;
    t.j0[o] = j; t.fj[o] = x - (float)j;
  }
  return t;
}
constexpr UpT UT = mkUp();

__device__ __forceinline__ void upfac(int o, int& j0, float& f){
  float x = ((float)o + 0.5f)*0.515625f - 0.5f;
  x = fminf(fmaxf(x, 0.f), 32.f);
  int j = (int)x; j = j < 31 ? j : 31;
  j0 = j; f = x - (float)j;
}

__device__ __forceinline__ void fma8(float (&a)[8], float qv, const float4& q0, const float4& q1){
  a[0] += qv*q0.x; a[1] += qv*q0.y; a[2] += qv*q0.z; a[3] += qv*q0.w;
  a[4] += qv*q1.x; a[5] += qv*q1.y; a[6] += qv*q1.z; a[7] += qv*q1.w;
}
__device__ __forceinline__ void fma8h(float (&a)[8], float qv, uint4 u){
  a[0] += qv*b2f((u16)(u.x&0xFFFFu)); a[1] += qv*b2f((u16)(u.x>>16));
  a[2] += qv*b2f((u16)(u.y&0xFFFFu)); a[3] += qv*b2f((u16)(u.y>>16));
  a[4] += qv*b2f((u16)(u.z&0xFFFFu)); a[5] += qv*b2f((u16)(u.z>>16));
  a[6] += qv*b2f((u16)(u.w&0xFFFFu)); a[7] += qv*b2f((u16)(u.w>>16));
}

// ---------------- k_pre: tables + 3x weight cvt + x transpose (5 launches -> 1) ----------------
__global__ __launch_bounds__(256) void k_pre(const float* __restrict__ x, const float* __restrict__ qkvw,
                                             const float* __restrict__ w1, const float* __restrict__ w2,
                                             float* __restrict__ W127, float* __restrict__ W64,
                                             u16* __restrict__ wqb, u16* __restrict__ w1b,
                                             u16* __restrict__ w2b, u16* __restrict__ xq){
  int blk = blockIdx.x, tid = threadIdx.x;
  if (blk == 0){
    int i = tid;
    if (i < 33){
      const float inv = 127.0f/33.0f;
      float xx = ((float)i + 0.5f)*inv - 0.5f;
      float s = 0.f;
      for (int j=0;j<127;++j){ float w = 1.0f - fabsf((float)j - xx)/inv; w = fmaxf(w,0.f); W127[i*127+j]=w; s+=w; }
      float r = 1.0f/s;
      for (int j=0;j<127;++j) W127[i*127+j] *= r;
    } else if (i < 66){
      int ii = i-33;
      const float inv = 64.0f/33.0f;
      float xx = ((float)ii + 0.5f)*inv - 0.5f;
      float s=0.f;
      for (int j=0;j<64;++j){ float w = 1.0f - fabsf((float)j - xx)/inv; w=fmaxf(w,0.f); W64[ii*64+j]=w; s+=w; }
      float r=1.0f/s;
      for (int j=0;j<64;++j) W64[ii*64+j]*=r;
    }
  } else if (blk < 129){
    int id = (blk-1)*256 + tid;
    if (id < 32768) wqb[id] = f2b(qkvw[id]);
  } else if (blk < 385){
    int id = (blk-129)*256 + tid;
    if (id < 65536) w1b[id] = f2b(w1[id]);
  } else if (blk < 641){
    int id = (blk-385)*256 + tid;
    if (id < 65536) w2b[id] = f2b(w2[id]);
  } else {
    __shared__ float T[128][66];
    int bx = blk - 641;
    int n = bx>>6, h = bx&63;
    for (int e=tid;e<8192;e+=256){
      int c = e>>6, w = e&63;                  // 64-float contiguous reads per c
      T[c][w] = x[(((size_t)(n*128+c))*64 + h)*64 + w];
    }
    __syncthreads();
    for (int e=tid;e<8192;e+=256){
      int w = e>>7, c = e&127;                 // 256B contiguous u16 stores per w
      xq[(((size_t)(n*64+w))*64 + h)*128 + c] = f2b(T[c][w]);
    }
  }
}

// ---------------- k_qkvp1: QKV MFMA GEMM (blk<512) + pos1 (blk 512..1035) ----------------
__global__ __launch_bounds__(256) void k_qkvp1(const u16* __restrict__ xq, const u16* __restrict__ wqb,
                                               u16* __restrict__ qkvT, float2* __restrict__ part,
                                               const float* __restrict__ base, const float* __restrict__ W127,
                                               float* __restrict__ tmp){
  if (blockIdx.x < 512){
    int b = blockIdx.x;
    int tid = threadIdx.x;
    int wv = tid>>6, l = tid&63;
    int wn = wv*64;
    int lr = l&15, lq = l>>4;
    __shared__ u16 As[64*40];
    __shared__ u16 Bs[256*40];
    f32x4 acc[4][4];
    #pragma unroll
    for (int mi=0;mi<4;++mi)
      #pragma unroll
      for (int ni=0;ni<4;++ni) acc[mi][ni] = (f32x4){0.f,0.f,0.f,0.f};
    const u16* Ag = xq + (size_t)b*8192;      // [64][128]
    const u16* Bg = wqb;                       // [256][128]
    for (int ks=0; ks<128; ks+=32){
      __syncthreads();
      { int e = tid; int row = e>>2, q = e&3;
        *(uint4*)&As[row*40 + q*8] = *(const uint4*)&Ag[(size_t)row*128 + ks + q*8]; }
      #pragma unroll
      for (int p=0;p<4;++p){
        int e = tid + p*256; int row = e>>2, q = e&3;
        *(uint4*)&Bs[row*40 + q*8] = *(const uint4*)&Bg[(size_t)row*128 + ks + q*8];
      }
      __syncthreads();
      bf16x8 af[4], bfr[4];
      #pragma unroll
      for (int mi=0;mi<4;++mi) af[mi] = *(const bf16x8*)&As[(mi*16 + lr)*40 + lq*8];
      #pragma unroll
      for (int ni=0;ni<4;++ni) bfr[ni] = *(const bf16x8*)&Bs[(wn + ni*16 + lr)*40 + lq*8];
      #pragma unroll
      for (int mi=0;mi<4;++mi)
        #pragma unroll
        for (int ni=0;ni<4;++ni)
          acc[mi][ni] = __builtin_amdgcn_mfma_f32_16x16x32_bf16(af[mi], bfr[ni], acc[mi][ni], 0,0,0);
    }
    // epilogue: bf16 C store + per-channel (o) fp32 partial sums over l (this b)
    float cs[4] = {0.f,0.f,0.f,0.f}, cq[4] = {0.f,0.f,0.f,0.f};
    u16* ob = qkvT + (size_t)b*16384;
    #pragma unroll
    for (int mi=0;mi<4;++mi)
      #pragma unroll
      for (int r=0;r<4;++r){
        int row = mi*16 + lq*4 + r;
        #pragma unroll
        for (int ni=0;ni<4;++ni){
          float v = acc[mi][ni][r];
          ob[(size_t)row*256 + wn + ni*16 + lr] = f2b(v);
          cs[ni] += v; cq[ni] += v*v;
        }
      }
    #pragma unroll
    for (int ni=0;ni<4;++ni){
      cs[ni] += __shfl_xor(cs[ni], 16); cs[ni] += __shfl_xor(cs[ni], 32);
      cq[ni] += __shfl_xor(cq[ni], 16); cq[ni] += __shfl_xor(cq[ni], 32);
    }
    if (lq == 0){
      #pragma unroll
      for (int ni=0;ni<4;++ni)
        part[(size_t)(wn + ni*16 + lr)*512 + b] = make_float2(cs[ni], cq[ni]);
    }
  } else {
    int id = (blockIdx.x-512)*256 + threadIdx.x;
    if (id >= 32*33*127) return;
    int c = id / 4191; int r = id - c*4191; int i = r / 127; int xx = r - i*127;
    const float* wr = W127 + i*127;
    const float* bc = base + c*16129 + xx;
    float a=0.f;
    for (int y=0;y<127;++y) a += wr[y]*bc[y*127];
    tmp[id] = a;
  }
}

// ---------------- k_st2p2: qkv BN stats (blk<8) + pos2 (blk 8..144) ----------------
__global__ __launch_bounds__(256) void k_st2p2(const float2* __restrict__ part, const float* __restrict__ g,
                                               const float* __restrict__ bta, float2* __restrict__ st,
                                               const float* __restrict__ tmp, const float* __restrict__ W127,
                                               float* __restrict__ pos){
  if (blockIdx.x < 8){
    int t = threadIdx.x;
    int chL = t>>3, seg = t&7;
    int ch = blockIdx.x*32 + chL;
    float s=0.f, s2=0.f;
    const float2* p = part + (size_t)ch*512 + seg*64;
    #pragma unroll 8
    for (int r=0;r<64;++r){ float2 q = p[r]; s+=q.x; s2+=q.y; }
    __shared__ float A[32][9], Bq[32][9];
    A[chL][seg]=s; Bq[chL][seg]=s2; __syncthreads();
    if (seg==0){
      #pragma unroll
      for (int k=1;k<8;++k){ s += A[chL][k]; s2 += Bq[chL][k]; }
      float m = s*(1.0f/32768.0f);
      float var = s2*(1.0f/32768.0f) - m*m;
      float sc = g[ch]/sqrtf(var + EPSV);
      st[ch] = make_float2(sc, bta[ch] - m*sc);
    }
  } else {
    int id = (blockIdx.x-8)*256 + threadIdx.x;
    if (id >= 32*33*33) return;
    int c = id / 1089; int r = id - c*1089; int i = r / 33; int j = r - i*33;
    const float* wr = W127 + j*127;
    const float* tc = tmp + c*4191 + i*127;
    float a=0.f;
    for (int xx=0;xx<127;++xx) a += wr[xx]*tc[xx];
    pos[id] = a;
  }
}

// ---------------- k_qkvr_kv: qkvr (blk<512) + keT (512..546) + veP (547..678) ----------------
__global__ __launch_bounds__(256) void k_qkvr_kv(const u16* __restrict__ qkvT, const float* __restrict__ W64,
                                                 const float2* __restrict__ st, u16* __restrict__ qkvrT,
                                                 const float* __restrict__ pos, float* __restrict__ keT,
                                                 u16* __restrict__ VeP){
  int blk = blockIdx.x;
  if (blk < 512){
    int b = blk, ch = threadIdx.x;
    const u16* base = qkvT + (size_t)b*16384 + ch;
    float xr[64];
    #pragma unroll
    for (int t=0;t<64;++t) xr[t] = b2f(base[t*256]);
    float2 sb = st[ch];
    u16* ob = qkvrT + (size_t)b*8448 + ch;
    for (int i=0;i<33;++i){
      const float4* wr = (const float4*)(W64 + i*64);
      float a = 0.f;
      #pragma unroll
      for (int q=0;q<16;++q){
        float4 w4 = wr[q];
        a += w4.x*xr[4*q] + w4.y*xr[4*q+1] + w4.z*xr[4*q+2] + w4.w*xr[4*q+3];
      }
      ob[i*256] = f2b(a*sb.x + sb.y);
    }
  } else if (blk < 547){
    int id = (blk-512)*256 + threadIdx.x;
    if (id >= 8712) return;
    int c = id / 1089; int r = id - c*1089; int i = r / 33; int j = r - i*33;
    keT[id] = pos[(8+c)*1089 + j*33 + i];
  } else {
    int id = (blk-547)*256 + threadIdx.x;
    if (id >= 33792) return;
    int c = id & 15;
    int i = (id >> 4) & 63;
    int k = id >> 10;
    int i0; float fi; upfac(i, i0, fi);
    const float* P = pos + (16+c)*1089;
    VeP[id] = f2b((1.f-fi)*P[i0*33 + k] + fi*P[(i0+1)*33 + k]);
  }
}

// ---------------- sim = concat([qk, qr, kr]) bf16 + per-block stats partials (fp32) ----------------
__global__ __launch_bounds__(256) void k_sim(const u16* __restrict__ qkvrT, const float* __restrict__ pos,
                                             const float* __restrict__ keT,
                                             u16* __restrict__ sim, float* __restrict__ part6){
  int b = blockIdx.x, g = blockIdx.y;
  __shared__ float lqa[264], lka[264];
  int tid = threadIdx.x;
  for (int e=tid;e<528;e+=256){
    int half = (e < 264) ? 0 : 1;
    int e2 = e - half*264;
    int c = e2/33, i = e2 - c*33;
    float v = b2f(qkvrT[(size_t)b*8448 + i*256 + (g*32 + half*8 + c)]);
    if (half==0) lqa[e2]=v; else lka[e2]=v;
  }
  __syncthreads();
  float sqk=0.f,qqk=0.f,sqr=0.f,qqr=0.f,skr=0.f,qkr=0.f;
  for (int p=tid;p<1089;p+=256){
    int i = p/33, j = p - i*33;
    float qk=0.f, qr=0.f, kr=0.f;
    #pragma unroll
    for (int c=0;c<8;++c){
      float qa_ = lqa[c*33+i];
      float ka_ = lka[c*33+j];
      qk += qa_*ka_;
      qr += qa_*pos[c*1089 + i*33 + j];
      kr += ka_*keT[c*1089 + i*33 + j];
    }
    sim[(size_t)(b*24 + g)*1089 + p] = f2b(qk);
    sim[(size_t)(b*24 + 8 + g)*1089 + p] = f2b(qr);
    sim[(size_t)(b*24 + 16 + g)*1089 + p] = f2b(kr);
    sqk+=qk; qqk+=qk*qk; sqr+=qr; qqr+=qr*qr; skr+=kr; qkr+=kr*kr;
  }
  __shared__ float red[6][256];
  red[0][tid]=sqk; red[1][tid]=qqk; red[2][tid]=sqr;
  red[3][tid]=qqr; red[4][tid]=skr; red[5][tid]=qkr;
  __syncthreads();
  for (int o=128;o>0;o>>=1){
    if (tid<o){
      #pragma unroll
      for (int c=0;c<6;++c) red[c][tid]+=red[c][tid+o];
    }
    __syncthreads();
  }
  if (tid<6) part6[(size_t)(b*8+g)*6 + tid] = red[tid][0];
}

// ---------------- simst from part6 ----------------
__global__ void k_sstB(const float* __restrict__ part6, const float* __restrict__ g,
                       const float* __restrict__ bta, float2* __restrict__ st){
  int nb = threadIdx.x;
  if (nb >= 192) return;
  int n = nb/24, ch = nb - n*24;
  int t3 = ch>>3, gg = ch&7;
  float s=0.f, s2=0.f;
  for (int w=0; w<64; ++w){
    const float* p = part6 + (size_t)((n*64+w)*8 + gg)*6 + 2*t3;
    s += p[0]; s2 += p[1];
  }
  float m = s*(1.0f/69696.0f);
  float var = s2*(1.0f/69696.0f) - m*m;
  float sc = g[ch]/sqrtf(var + EPSV);
  st[nb] = make_float2(sc, bta[ch] - m*sc);
}

// ---------------- fused attention v11: 128-thread blocks (1 bg, 2 waves = channel halves) --------
// Same arithmetic as the r26-measured kernel; block geometry 256->128 removes the
// __launch_bounds__(256,4) metadata occupancy cap (plain bounds -> residency from actual
// usage: 48 VGPR, 6.5KB LDS -> 16 blocks/CU allowed). Grid 4096 = one full round.
__global__ __launch_bounds__(128) void k_attn(const u16* __restrict__ sim, const float2* __restrict__ simst,
                                              const u16* __restrict__ qkvrT, const u16* __restrict__ veP,
                                              u16* __restrict__ so){
  int tid = threadIdx.x;
  int half = tid >> 6;     // channel half: 0 -> c 0..7, 1 -> c 8..15
  int i  = tid & 63;
  __shared__ float  S[1092];
  __shared__ float4 Va[132];
  // cooperative staging of this bg tile
  {
    int bg2 = blockIdx.x;
    int b2 = bg2>>3, g2 = bg2&7, n2 = b2>>6;
    float2 sb0 = simst[n2*24 + g2], sb1 = simst[n2*24 + 8 + g2], sb2 = simst[n2*24 + 16 + g2];
    float badd = sb0.y + sb1.y + sb2.y;
    const u16* s0 = sim + ((size_t)b2*24 + g2)*1089;
    for (int e=tid;e<1089;e+=128)
      S[e] = b2f(s0[e])*sb0.x + b2f(s0[e+8712])*sb1.x + b2f(s0[e+17424])*sb2.x + badd;
    for (int e=tid;e<132;e+=128){
      int j = e>>2, cq = e&3;
      const u16* qp = qkvrT + (size_t)b2*8448 + j*256 + g2*32 + 16 + cq*4;
      uint2 u = *(const uint2*)qp;
      Va[e] = make_float4(b2f((u16)(u.x&0xFFFFu)), b2f((u16)(u.x>>16)),
                          b2f((u16)(u.y&0xFFFFu)), b2f((u16)(u.y>>16)));
    }
  }
  __syncthreads();

  int bg = blockIdx.x;
  int b = bg>>3, g = bg&7;

  // phase A: i-lerped score row, exp, fold into qk[33] (duplicated across the wave pair)
  int i0; float fi; upfac(i, i0, fi);
  const float* R0 = S + i0*33;
  float rowv[33];
  #pragma unroll
  for (int k=0;k<33;++k) rowv[k] = R0[k] + fi*(R0[k+33] - R0[k]);
  float qk[33];
  #pragma unroll
  for (int k=0;k<33;++k) qk[k] = 0.f;
  float s = 0.f;
  #pragma unroll
  for (int j=0;j<64;++j){
    float fj = UT.fj[j]; int j0 = UT.j0[j];
    float v = rowv[j0] + fj*(rowv[j0+1] - rowv[j0]);
    float e = __expf(v);
    s += e;
    qk[j0]   += e*(1.f-fj);
    qk[j0+1] += e*fj;
  }
  float inv = 1.f/s;

  // phase B: this wave's 8-channel half; chunk-of-11 loads (compiler schedules ~3 in flight)
  float av[8], ae[8];
  #pragma unroll
  for (int c=0;c<8;++c){ av[c]=0.f; ae[c]=0.f; }
  const uint4* vp  = (const uint4*)veP + (size_t)i*2 + half;   // one uint4 (8 ch) per k
  const float4* va4 = &Va[half*2];                              // two float4 (8 ch) per k
  #pragma unroll
  for (int kc=0; kc<33; kc+=11){
    uint4 e0 = vp[(kc+0)*128],  e1 = vp[(kc+1)*128],  e2 = vp[(kc+2)*128];
    uint4 e3 = vp[(kc+3)*128],  e4 = vp[(kc+4)*128],  e5 = vp[(kc+5)*128];
    uint4 e6 = vp[(kc+6)*128],  e7 = vp[(kc+7)*128],  e8 = vp[(kc+8)*128];
    uint4 e9 = vp[(kc+9)*128],  e10= vp[(kc+10)*128];
    // LDS-fed work covers global latency
    #pragma unroll
    for (int t2=0;t2<11;++t2)
      fma8(av, qk[kc+t2], va4[(kc+t2)*4+0], va4[(kc+t2)*4+1]);
    // consume globals (unpack bf16)
    fma8h(ae, qk[kc+0], e0);  fma8h(ae, qk[kc+1], e1);  fma8h(ae, qk[kc+2], e2);
    fma8h(ae, qk[kc+3], e3);  fma8h(ae, qk[kc+4], e4);  fma8h(ae, qk[kc+5], e5);
    fma8h(ae, qk[kc+6], e6);  fma8h(ae, qk[kc+7], e7);  fma8h(ae, qk[kc+8], e8);
    fma8h(ae, qk[kc+9], e9);  fma8h(ae, qk[kc+10], e10);
  }
  u16* ob = so + (size_t)b*16384 + g*2048 + (half*8)*128;
  #pragma unroll
  for (int c=0;c<8;++c){
    ob[c*128 + i]      = f2b(av[c]*inv);
    ob[c*128 + 64 + i] = f2b(ae[c]*inv);
  }
}

// ---------------- so BN stats, 2-stage (bf16 so) ----------------
__global__ __launch_bounds__(256) void k_sost1(const u16* __restrict__ so, float2* __restrict__ part){
  int ch = blockIdx.x, rowG = blockIdx.y;   // 256 x 8
  int tid = threadIdx.x;
  int rs = tid>>6, l = tid&63;
  float s=0.f, s2=0.f;
  for (int r = rowG*64 + rs; r < rowG*64 + 64; r += 4){
    float v = b2f(so[((size_t)r*256 + ch)*64 + l]); s+=v; s2+=v*v;
  }
  __shared__ float S1[256], S2[256];
  S1[tid]=s; S2[tid]=s2; __syncthreads();
  for (int o=128;o>0;o>>=1){ if(tid<o){ S1[tid]+=S1[tid+o]; S2[tid]+=S2[tid+o]; } __syncthreads(); }
  if (tid==0) part[ch*8 + rowG] = make_float2(S1[0], S2[0]);
}
__global__ void k_sost2(const float2* __restrict__ part, const float* __restrict__ g,
                        const float* __restrict__ bta, float2* __restrict__ st){
  int ch = threadIdx.x;   // 256
  float s=0.f, s2=0.f;
  #pragma unroll
  for (int r=0;r<8;++r){ float2 p = part[ch*8 + r]; s+=p.x; s2+=p.y; }
  float m = s*(1.0f/32768.0f);
  float var = s2*(1.0f/32768.0f) - m*m;
  float sc = g[ch]/sqrtf(var + EPSV);
  st[ch] = make_float2(sc, bta[ch] - m*sc);
}

// ---------------- BN(so) + pair-sum + transpose -> o + xo-stats partials ----------------
__global__ __launch_bounds__(256) void k_o(const u16* __restrict__ so, const float2* __restrict__ st,
                                           float* __restrict__ o, float* __restrict__ opart){
  __shared__ float T[64][65];
  __shared__ float R1[256], R2[256];
  int n = blockIdx.x>>7, oc = blockIdx.x&127;
  int tid = threadIdx.x;
  float2 s0 = st[2*oc], s1 = st[2*oc+1];
  float badd = s0.y + s1.y;
  for (int e=tid;e<4096;e+=256){
    int w = e>>6, h = e&63;                  // lanes along h: contiguous so reads
    const u16* sb = so + (size_t)(n*64+w)*16384 + (2*oc)*64;
    T[w][h] = b2f(sb[h])*s0.x + b2f(sb[64+h])*s1.x + badd;
  }
  __syncthreads();
  for (int e=tid;e<4096;e+=256){
    int h = e>>6, w = e&63;                  // lanes along w: contiguous o writes
    o[(((size_t)(n*128+oc))*64 + h)*64 + w] = T[w][h];
  }
  // ---- stats partials (T intact) ----
  float fs=0.f, fq=0.f;
  for (int e=tid;e<4096;e+=256){ float v = T[e>>6][e&63]; fs+=v; fq+=v*v; }
  R1[tid]=fs; R2[tid]=fq; __syncthreads();
  for (int o2=128;o2>0;o2>>=1){ if(tid<o2){ R1[tid]+=R1[tid+o2]; R2[tid]+=R2[tid+o2]; } __syncthreads(); }
  float* rec = opart + (size_t)(n*128+oc)*18;
  if (tid==0){ rec[0]=R1[0]; rec[1]=R2[0]; }
  if (tid < 64){
    int l = tid;                             // wave 0, lane l = h index
    float c0=T[0][l], c1=T[1][l], c62=T[62][l], c63=T[63][l];
    float d0=c0*c0, d1=c1*c1, d62=c62*c62, d63=c63*c63;
    #pragma unroll
    for (int off=32; off; off>>=1){
      c0+=__shfl_xor(c0,off); c1+=__shfl_xor(c1,off);
      c62+=__shfl_xor(c62,off); c63+=__shfl_xor(c63,off);
      d0+=__shfl_xor(d0,off); d1+=__shfl_xor(d1,off);
      d62+=__shfl_xor(d62,off); d63+=__shfl_xor(d63,off);
    }
    if (l==0){
      rec[2]=c0; rec[3]=d0; rec[4]=c1; rec[5]=d1;
      rec[6]=c62; rec[7]=d62; rec[8]=c63; rec[9]=d63;
    }
  } else if (tid < 128){
    int l = tid & 63;                        // wave 1, lane l = w index
    float r0=T[l][0], r1=T[l][1], r62=T[l][62], r63=T[l][63];
    float e0=r0*r0, e1=r1*r1, e62=r62*r62, e63=r63*r63;
    #pragma unroll
    for (int off=32; off; off>>=1){
      r0+=__shfl_xor(r0,off); r1+=__shfl_xor(r1,off);
      r62+=__shfl_xor(r62,off); r63+=__shfl_xor(r63,off);
      e0+=__shfl_xor(e0,off); e1+=__shfl_xor(e1,off);
      e62+=__shfl_xor(e62,off); e63+=__shfl_xor(e63,off);
    }
    if (l==0){
      rec[10]=r0; rec[11]=e0; rec[12]=r1; rec[13]=e1;
      rec[14]=r62; rec[15]=e62; rec[16]=r63; rec[17]=e63;
    }
  }
}

// ---------------- xo instance-norm stats from k_o plane records ----------------
__global__ void k_instB(const float* __restrict__ opart, const float* __restrict__ g,
                        const float* __restrict__ bta, float2* __restrict__ st){
  int nb = blockIdx.x*256 + threadIdx.x;
  if (nb >= 1024) return;
  int n = nb>>7, c = nb&127;
  float s, q;
  if (c >= 40){
    const float* r = opart + (size_t)(n*128+c)*18;
    s = r[0]; q = r[1];
  } else {
    int grp = c/10, cc = c - grp*10;
    const float* r = opart + (size_t)(n*128+cc)*18;
    if (grp==0){ s = r[0]-r[6]-r[8];   q = r[1]-r[7]-r[9];  }
    else if (grp==1){ s = r[0]-r[2]-r[4];   q = r[1]-r[3]-r[5];  }
    else if (grp==2){ s = r[0]-r[14]-r[16]; q = r[1]-r[15]-r[17];}
    else            { s = r[0]-r[10]-r[12]; q = r[1]-r[11]-r[13];}
  }
  float m = s*(1.0f/4096.0f);
  float var = q*(1.0f/4096.0f) - m*m;
  float sc = g[c]/sqrtf(var + EPSV);
  st[nb] = make_float2(sc, bta[c] - m*sc);
}

// ---------------- spatial block ----------------
__device__ __forceinline__ float xo_val(const float* __restrict__ o, int n, int c, int h, int w){
  if (c >= 40) return o[((n*128 + c)*64 + h)*64 + w];
  int grp = c / 10;
  int cc = c - grp*10;
  int base = (n*128 + cc)*64;
  if (grp==0) return (w>=2) ? o[(base + h)*64 + (w-2)] : 0.f;
  if (grp==1) return (w<62) ? o[(base + h)*64 + (w+2)] : 0.f;
  if (grp==2) return (h>=2) ? o[(base + (h-2))*64 + w] : 0.f;
  return (h<62) ? o[(base + (h+2))*64 + w] : 0.f;
}

// ---------------- fused: instance-norm(xo) + transpose -> xnT bf16 [n][hw][c] ----------------
__global__ __launch_bounds__(256) void k_xnt(const float* __restrict__ o, const float2* __restrict__ st,
                                             u16* __restrict__ xnT){
  __shared__ float T[64][65];
  int h = blockIdx.x&63, c0 = ((blockIdx.x>>6)&1)*64, n = blockIdx.x>>7;
  int tid = threadIdx.x;
  for (int e=tid;e<4096;e+=256){
    int cL = e>>6, w = e&63;                 // lanes along w: coalesced xo_val reads
    float2 sb = st[n*128 + c0+cL];           // wave-uniform
    T[cL][w] = xo_val(o, n, c0+cL, h, w)*sb.x + sb.y;
  }
  __syncthreads();
  for (int e=tid;e<4096;e+=256){
    int wL = e>>6, cL = e&63;                // lanes along c: 128B contiguous stores
    xnT[((size_t)(n*4096 + h*64 + wL))*128 + c0 + cL] = f2b(T[cL][wL]);
  }
}

// ---------------- mlp1: D[128 hw][64 co] per block, 4 waves (2x2 of 64x32); grid (32,8,8)=2048 ----
__global__ __launch_bounds__(256) void k_mlp1(const u16* __restrict__ xnT, const u16* __restrict__ w1b,
                                              u16* __restrict__ h1T){
  int hw0 = blockIdx.x*128, co0 = blockIdx.y*64, n = blockIdx.z;
  int tid = threadIdx.x;
  int wv = tid>>6, l = tid&63;
  int wm = (wv>>1)*64, wn = (wv&1)*32;
  int lr = l&15, lq = l>>4;
  __shared__ u16 As[128*40];
  __shared__ u16 Bs[64*40];
  f32x4 acc[4][2];
  #pragma unroll
  for (int mi=0;mi<4;++mi)
    #pragma unroll
    for (int ni=0;ni<2;++ni) acc[mi][ni] = (f32x4){0.f,0.f,0.f,0.f};
  const u16* Ag = xnT + ((size_t)(n*4096 + hw0))*128;
  const u16* Bg = w1b + (size_t)co0*128;
  for (int ks=0; ks<128; ks+=32){
    __syncthreads();
    #pragma unroll
    for (int p=0;p<2;++p){
      int e = tid + p*256; int row = e>>2, q = e&3;
      *(uint4*)&As[row*40 + q*8] = *(const uint4*)&Ag[(size_t)row*128 + ks + q*8];
    }
    { int e = tid; int row = e>>2, q = e&3;
      *(uint4*)&Bs[row*40 + q*8] = *(const uint4*)&Bg[(size_t)row*128 + ks + q*8]; }
    __syncthreads();
    bf16x8 af[4], bfr[2];
    #pragma unroll
    for (int mi=0;mi<4;++mi) af[mi] = *(const bf16x8*)&As[(wm + mi*16 + lr)*40 + lq*8];
    #pragma unroll
    for (int ni=0;ni<2;++ni) bfr[ni] = *(const bf16x8*)&Bs[(wn + ni*16 + lr)*40 + lq*8];
    #pragma unroll
    for (int mi=0;mi<4;++mi)
      #pragma unroll
      for (int ni=0;ni<2;++ni)
        acc[mi][ni] = __builtin_amdgcn_mfma_f32_16x16x32_bf16(af[mi], bfr[ni], acc[mi][ni], 0,0,0);
  }
  u16* ob = h1T + ((size_t)(n*4096 + hw0 + wm))*512 + co0 + wn;
  #pragma unroll
  for (int mi=0;mi<4;++mi)
    #pragma unroll
    for (int r=0;r<4;++r){
      int row = mi*16 + lq*4 + r;
      #pragma unroll
      for (int ni=0;ni<2;++ni){
        float v = acc[mi][ni][r];
        ob[(size_t)row*512 + ni*16 + lr] = f2b(gelu_f(v));
      }
    }
}

// ---------------- mlp2: split-K(2) + hw-tile 64; grid (64,2,8)=1024, atomicAdd commit ----
__global__ __launch_bounds__(256) void k_mlp2(const u16* __restrict__ w2b, const u16* __restrict__ h1T,
                                              float* __restrict__ out){
  int hw0 = blockIdx.x*64, n = blockIdx.z;
  int ks0 = blockIdx.y*256;                 // K half: [ks0, ks0+256)
  int tid = threadIdx.x;
  int wv = tid>>6, l = tid&63;
  int wm = (wv>>1)*64, wn = (wv&1)*32;      // wm: co offset, wn: hw offset
  int lr = l&15, lq = l>>4;
  __shared__ u16 As[128*40];
  __shared__ u16 Bs[64*40];
  f32x4 acc[4][2];
  #pragma unroll
  for (int mi=0;mi<4;++mi)
    #pragma unroll
    for (int ni=0;ni<2;++ni) acc[mi][ni] = (f32x4){0.f,0.f,0.f,0.f};
  const u16* Ag = w2b;
  const u16* Bg = h1T + ((size_t)(n*4096 + hw0))*512;
  for (int ks=ks0; ks<ks0+256; ks+=32){
    __syncthreads();
    #pragma unroll
    for (int p=0;p<2;++p){
      int e = tid + p*256; int row = e>>2, q = e&3;
      *(uint4*)&As[row*40 + q*8] = *(const uint4*)&Ag[(size_t)row*512 + ks + q*8];
    }
    { int e = tid; int row = e>>2, q = e&3;
      *(uint4*)&Bs[row*40 + q*8] = *(const uint4*)&Bg[(size_t)row*512 + ks + q*8]; }
    __syncthreads();
    bf16x8 af[4], bfr[2];
    #pragma unroll
    for (int mi=0;mi<4;++mi) af[mi] = *(const bf16x8*)&As[(wm + mi*16 + lr)*40 + lq*8];
    #pragma unroll
    for (int ni=0;ni<2;++ni) bfr[ni] = *(const bf16x8*)&Bs[(wn + ni*16 + lr)*40 + lq*8];
    #pragma unroll
    for (int mi=0;mi<4;++mi)
      #pragma unroll
      for (int ni=0;ni<2;++ni)
        acc[mi][ni] = __builtin_amdgcn_mfma_f32_16x16x32_bf16(af[mi], bfr[ni], acc[mi][ni], 0,0,0);
  }
  #pragma unroll
  for (int mi=0;mi<4;++mi)
    #pragma unroll
    for (int r=0;r<4;++r){
      int cout = wm + mi*16 + lq*4 + r;
      #pragma unroll
      for (int ni=0;ni<2;++ni){
        size_t idx = ((size_t)(n*128 + cout))*4096 + hw0 + wn + ni*16 + lr;
        atomicAdd(&out[idx], acc[mi][ni][r]);
      }
    }
}

extern "C" void kernel_launch(void* const* d_in, const int* in_sizes, int n_in,
                              void* d_out, int out_size, void* d_ws, size_t ws_size,
                              hipStream_t stream) {
  (void)in_sizes; (void)n_in; (void)out_size; (void)ws_size;
  const float* x       = (const float*)d_in[0];
  const float* qkvw    = (const float*)d_in[1];
  const float* bng     = (const float*)d_in[2];
  const float* bnb     = (const float*)d_in[3];
  const float* baserel = (const float*)d_in[4];
  const float* simg    = (const float*)d_in[5];
  const float* simb    = (const float*)d_in[6];
  const float* outg    = (const float*)d_in[7];
  const float* outb    = (const float*)d_in[8];
  const float* ing     = (const float*)d_in[9];
  const float* inb     = (const float*)d_in[10];
  const float* w1      = (const float*)d_in[11];
  const float* w2      = (const float*)d_in[12];

  float* ws = (float*)d_ws;
  float*  W127  = ws + F_W127;
  float*  W64   = ws + F_W64;
  float2* qkvst = (float2*)(ws + F_QKVST);
  float2* simst = (float2*)(ws + F_SIMST);
  float2* sost  = (float2*)(ws + F_SOST);
  float2* inst  = (float2*)(ws + F_INST);
  float*  postmp= ws + F_POSTMP;
  float*  pos   = ws + F_POS;
  u16*    qkvT  = (u16*)(ws + F_QKV);
  u16*    qkvrT = (u16*)(ws + F_QKVR);
  u16*    sim   = (u16*)(ws + F_SIM);
  float*  part6 = ws + F_PART6;
  float2* sopart= (float2*)(ws + F_PART6);   // reuse after k_sstB (part6 dead)
  float2* bnp   = (float2*)(ws + F_BNP2);    // qkv BN partials (k_qkvp1..k_st2p2)
  float*  opart = ws + F_BNP2;               // plane stat records (k_o..k_instB); bnp dead by then
  u16*    wqb   = (u16*)(ws + F_WQB);        // bf16 qkv weight
  u16*    veP   = (u16*)(ws + F_VEH);
  u16*    xnT   = (u16*)(ws + F_XNT);
  float*  keT   = ws + F_KET;
  u16*    so    = (u16*)(ws + F_SO);
  u16*    xq    = (u16*)(ws + F_XQ);
  u16*    h1T   = (u16*)(ws + F_H1);
  u16*    w1b   = (u16*)(ws + F_W1B);        // in PART6 dead sub-range (>= +1048576)
  u16*    w2b   = (u16*)(ws + F_W2B);
  float*  out   = (float*)d_out;

  k_pre     <<<dim3(1153),     dim3(256), 0, stream>>>(x, qkvw, w1, w2, W127, W64, wqb, w1b, w2b, xq);
  k_qkvp1   <<<dim3(1036),     dim3(256), 0, stream>>>(xq, wqb, qkvT, bnp, baserel, W127, postmp);
  k_st2p2   <<<dim3(145),      dim3(256), 0, stream>>>(bnp, bng, bnb, qkvst, postmp, W127, pos);
  k_qkvr_kv <<<dim3(679),      dim3(256), 0, stream>>>(qkvT, W64, qkvst, qkvrT, pos, keT, veP);
  k_sim     <<<dim3(512,8),    dim3(256), 0, stream>>>(qkvrT, pos, keT, sim, part6);
  k_sstB    <<<dim3(1),        dim3(192), 0, stream>>>(part6, simg, simb, simst);
  k_attn    <<<dim3(4096),     dim3(128), 0, stream>>>(sim, simst, qkvrT, veP, so);
  k_sost1   <<<dim3(256,8),    dim3(256), 0, stream>>>(so, sopart);
  k_sost2   <<<dim3(1),        dim3(256), 0, stream>>>(sopart, outg, outb, sost);
  k_o       <<<dim3(1024),     dim3(256), 0, stream>>>(so, sost, out, opart);
  k_instB   <<<dim3(4),        dim3(256), 0, stream>>>(opart, ing, inb, inst);
  k_xnt     <<<dim3(1024),     dim3(256), 0, stream>>>(out, inst, xnT);
  k_mlp1    <<<dim3(32,8,8),   dim3(256), 0, stream>>>(xnT, w1b, h1T);
  k_mlp2    <<<dim3(64,2,8),   dim3(256), 0, stream>>>(w2b, h1T, out);
}